// Round 17
// baseline (225.351 us; speedup 1.0000x reference)
//
#include <hip/hip_runtime.h>
#include <math.h>

#define B_SZ 2
#define L_LEN 2048
#define D_MOD 256
#define H_HEADS 8
#define NB_BLK 2
#define S_SZ 2
#define E_SZ 503
#define C_SZ 8
#define FIN 514
#define FIN_PAD 576
#define LOG2E 1.44269504088896340736f
#define QSC (0.125f * LOG2E)

typedef short bf16x8 __attribute__((ext_vector_type(8)));
typedef float f32x4 __attribute__((ext_vector_type(4)));
typedef unsigned short u16x4 __attribute__((ext_vector_type(4)));
typedef unsigned short u16x8 __attribute__((ext_vector_type(8)));

// bf16 weight buffer offsets (elements) inside wt
#define OFF_IN1 0           // [1024][576]
#define OFF_IN2 589824      // [256][1024]
#define OFF_QKV 851968      // [2][1536][256]  rows: 0-511 q(*QSC), 512-1023 k, 1024-1535 v
#define OFF_O   1638400     // [2][256][512]
#define OFF_F1  1900544     // [2][1024][256]
#define OFF_F2  2424832     // [2][256][1024]
#define OFF_H   2949120     // [128][768]  (Whi | Whi | Wlo)
#define WT_END  3047424

__device__ __forceinline__ unsigned short f2bf(float x) {
    unsigned u = __float_as_uint(x);
    u += 0x7FFFu + ((u >> 16) & 1u);
    return (unsigned short)(u >> 16);
}

__device__ __forceinline__ float bf2f(unsigned short h) {
    return __uint_as_float(((unsigned)h) << 16);
}

__device__ __forceinline__ float gelu_f(float x) {
    float x3 = x * x * x;
    return 0.5f * x * (1.0f + tanhf(0.7978845608028654f * (x + 0.044715f * x3)));
}

__device__ __forceinline__ void gll16(const void* g, void* l) {
    __builtin_amdgcn_global_load_lds(
        (const __attribute__((address_space(1))) unsigned int*)g,
        (__attribute__((address_space(3))) unsigned int*)l,
        16, 0, 0);
}

// ---------------------------------------------------------------------------
// Merged prep: [0,720) wprep | [720,1104) hprep | [1104,2128) km_frag (both i)
// | [2128,2140) bprep | [2140,3292) feats (both b, 4 elems/thread)
// km_frag layout: [i][kt*32+qb][lane 0..255][16 bf16]
// value[c*4+r] = LOG2E*bias_w[i]*Kmat[qb*64+16w+4g+r][kt*64+c*16+n16]
// ---------------------------------------------------------------------------
__global__ __launch_bounds__(256) void prep_kernel(
    const float* __restrict__ W_in1, const float* __restrict__ W_in2,
    const float* __restrict__ Wq, const float* __restrict__ Wk,
    const float* __restrict__ Wv, const float* __restrict__ Wo,
    const float* __restrict__ Wf1, const float* __restrict__ Wf2,
    const float* __restrict__ Wh1, const float* __restrict__ Kmat,
    const float* __restrict__ bias_w,
    const float* __restrict__ bq, const float* __restrict__ bk,
    const float* __restrict__ bv,
    const float* __restrict__ z, const float* __restrict__ s,
    const float* __restrict__ embed, const float* __restrict__ cond,
    unsigned short* __restrict__ wt, unsigned short* __restrict__ kmfrag,
    float* __restrict__ bqkv, unsigned short* __restrict__ feats)
{
    __shared__ unsigned short sT[64][65];
    int b = blockIdx.x;
    int t = threadIdx.x;

    if (b < 720) {
        // ---- weight transpose+cast ----
        const float* src; unsigned short* dst; int K, N, Kp, tile;
        float scale = 1.0f;
        if (b < 144)      { src = W_in1; dst = wt + OFF_IN1; K = 514;  N = 1024; Kp = 576;  tile = b; }
        else if (b < 208) { src = W_in2; dst = wt + OFF_IN2; K = 1024; N = 256;  Kp = 1024; tile = b - 144; }
        else if (b < 400) { int t2 = b - 208;
                            int sec = t2 >> 5; tile = t2 & 31;
                            int i = sec / 3, which = sec % 3;
                            const float* wsrc = which == 0 ? Wq : which == 1 ? Wk : Wv;
                            if (which == 0) scale = QSC;
                            src = wsrc + (size_t)i * 131072;
                            dst = wt + OFF_QKV + (size_t)i * 393216 + (size_t)which * 131072;
                            K = 256; N = 512; Kp = 256; }
        else if (b < 464) { int t2 = b - 400; int i = t2 >> 5; tile = t2 & 31;
                            src = Wo + (size_t)i * 131072; dst = wt + OFF_O + (size_t)i * 131072;
                            K = 512; N = 256; Kp = 512; }
        else if (b < 592) { int t2 = b - 464; int i = t2 >> 6; tile = t2 & 63;
                            src = Wf1 + (size_t)i * 262144; dst = wt + OFF_F1 + (size_t)i * 262144;
                            K = 256; N = 1024; Kp = 256; }
        else              { int t2 = b - 592; int i = t2 >> 6; tile = t2 & 63;
                            src = Wf2 + (size_t)i * 262144; dst = wt + OFF_F2 + (size_t)i * 262144;
                            K = 1024; N = 256; Kp = 1024; }

        int nt = N >> 6;
        int kt0 = (tile / nt) << 6;
        int nt0 = (tile % nt) << 6;
        #pragma unroll
        for (int p = 0; p < 4; p++) {
            int r = p * 16 + (t >> 4);
            int c = (t & 15) * 4;
            float4 v4 = make_float4(0.f, 0.f, 0.f, 0.f);
            if (kt0 + r < K) v4 = *(const float4*)(src + (size_t)(kt0 + r) * N + nt0 + c);
            sT[r][c + 0] = f2bf(v4.x * scale);
            sT[r][c + 1] = f2bf(v4.y * scale);
            sT[r][c + 2] = f2bf(v4.z * scale);
            sT[r][c + 3] = f2bf(v4.w * scale);
        }
        __syncthreads();
        int n = t >> 2, kq = (t & 3) * 16;
        u16x8 o0, o1;
        #pragma unroll
        for (int j = 0; j < 8; j++) {
            o0[j] = sT[kq + j][n];
            o1[j] = sT[kq + 8 + j][n];
        }
        unsigned short* dp = dst + (size_t)(nt0 + n) * Kp + kt0 + kq;
        *(u16x8*)(dp) = o0;
        *(u16x8*)(dp + 8) = o1;
    } else if (b < 1104) {
        // ---- head split-precision weights ----
        int idx = (b - 720) * 256 + t;   // 128*768
        if (idx < 128 * 768) {
            int n = idx / 768, kk = idx % 768;
            int kz = kk & 255;
            float v = Wh1[(size_t)kz * 128 + n];
            unsigned short hi = f2bf(v);
            wt[OFF_H + idx] = (kk < 512) ? hi : f2bf(v - bf2f(hi));
        }
    } else if (b < 2128) {
        // ---- km_frag: per-lane attention bias fragments, BOTH layers ----
        int tile = b - 1104;               // [0,1024)
        int kt = tile >> 5, qb = tile & 31;
        float s0 = bias_w[0] * LOG2E, s1 = bias_w[1] * LOG2E;
        int q0 = qb * 64 + ((t >> 6) << 4) + (((t >> 4) & 3) << 2);
        int k0 = kt * 64 + (t & 15);
        u16x8 a0, a1, b0, b1;
        #pragma unroll
        for (int c = 0; c < 4; c++)
            #pragma unroll
            for (int r = 0; r < 4; r++) {
                float v = Kmat[(size_t)(q0 + r) * L_LEN + k0 + c * 16];
                if (c < 2) { a0[c * 4 + r] = f2bf(v * s0); b0[c * 4 + r] = f2bf(v * s1); }
                else       { a1[(c - 2) * 4 + r] = f2bf(v * s0); b1[(c - 2) * 4 + r] = f2bf(v * s1); }
            }
        unsigned short* dp = kmfrag + (((size_t)(kt * 32 + qb)) * 256 + t) * 16;
        *(u16x8*)dp = a0;
        *(u16x8*)(dp + 8) = a1;
        unsigned short* dp1 = dp + ((size_t)1 << 22);
        *(u16x8*)dp1 = b0;
        *(u16x8*)(dp1 + 8) = b1;
    } else if (b < 2140) {
        // ---- fused QKV bias ----
        int idx = (b - 2128) * 256 + t;
        if (idx < 2 * 1536) {
            int i = idx / 1536, c = idx % 1536;
            float v;
            if (c < 512)       v = bq[i * 512 + c] * QSC;
            else if (c < 1024) v = bk[i * 512 + c - 512];
            else               v = bv[i * 512 + c - 1024];
            bqkv[idx] = v;
        }
    } else {
        // ---- feats: 4 elems/thread, both b rows from one read ----
        int idx = (b - 2140) * 256 + t;    // [0, 294912)
        int l = idx / 144;
        int f0 = (idx % 144) * 4;
        u16x4 pk0, pk1;
        #pragma unroll
        for (int j = 0; j < 4; j++) {
            int f = f0 + j;
            float val;
            if (f >= 3 && f < 506)      val = embed[(size_t)l * E_SZ + (f - 3)];
            else if (f >= 1 && f < 3)   val = s[l * S_SZ + (f - 1)];
            else if (f >= 506 && f < FIN) val = cond[f - 506];
            else                        val = 0.0f;
            unsigned short hv = f2bf(val);
            pk0[j] = (f == 0) ? f2bf(z[l]) : hv;
            pk1[j] = (f == 0) ? f2bf(z[L_LEN + l]) : hv;
        }
        *(u16x4*)(feats + (size_t)l * FIN_PAD + f0) = pk0;
        *(u16x4*)(feats + (size_t)(L_LEN + l) * FIN_PAD + f0) = pk1;
    }
}

// ---------------------------------------------------------------------------
// Wide-tile bf16 MFMA GEMM: 64x128 per block, 4 waves each 32x64 (2x4 frags),
// gll16 staging + XOR-swizzled LDS, double-buffered.
// OMODE: 1 = bf16 out, 4 = fused QKV routing
// ---------------------------------------------------------------------------
template<int ACT, int OMODE>
__global__ __launch_bounds__(256) void gemmW(
    const unsigned short* __restrict__ A, const unsigned short* __restrict__ Wt,
    const float* __restrict__ bias, unsigned short* __restrict__ Cb,
    unsigned short* __restrict__ Cbk, unsigned short* __restrict__ Cbv,
    int M, int N, int Kd, int lda)
{
    __shared__ unsigned short sA[2][64][64];
    __shared__ unsigned short sB[2][128][64];
    const int tid = threadIdx.x;
    const int l = tid & 63, w = tid >> 6;
    const int g = l >> 4, n16 = l & 15;
    const int wr = w >> 1, wc = w & 1;
    const int m0 = blockIdx.y * 64, n0 = blockIdx.x * 128;
    const int r8 = l >> 3;
    const int swz8 = ((l & 7) ^ r8) * 8;

    f32x4 acc[2][4];
    #pragma unroll
    for (int mi = 0; mi < 2; mi++)
        #pragma unroll
        for (int ni = 0; ni < 4; ni++)
            acc[mi][ni] = (f32x4){0.f, 0.f, 0.f, 0.f};

#define STAGEW(buf, k0)                                                         \
    do {                                                                        \
        _Pragma("unroll")                                                       \
        for (int p = 0; p < 2; p++) {                                           \
            int row = w * 16 + p * 8 + r8;                                      \
            gll16(A + (size_t)(m0 + row) * lda + (k0) + swz8,                   \
                  &sA[buf][w * 16 + p * 8][0]);                                 \
        }                                                                       \
        _Pragma("unroll")                                                       \
        for (int p = 0; p < 4; p++) {                                           \
            int row = w * 32 + p * 8 + r8;                                      \
            gll16(Wt + (size_t)(n0 + row) * Kd + (k0) + swz8,                   \
                  &sB[buf][w * 32 + p * 8][0]);                                 \
        }                                                                       \
    } while (0)

    STAGEW(0, 0);
    __syncthreads();

    int cur = 0;
    for (int k0 = 0; k0 < Kd; k0 += 64) {
        int nxt = cur ^ 1;
        if (k0 + 64 < Kd) STAGEW(nxt, k0 + 64);
        #pragma unroll
        for (int ks = 0; ks < 2; ks++) {
            bf16x8 af[2], bfr[4];
            #pragma unroll
            for (int mi = 0; mi < 2; mi++) {
                int row = wr * 32 + mi * 16 + n16;
                af[mi] = *(const bf16x8*)((const char*)&sA[cur][row][0]
                          + ((ks * 64 + g * 16) ^ ((n16 & 7) << 4)));
            }
            #pragma unroll
            for (int ni = 0; ni < 4; ni++) {
                int row = wc * 64 + ni * 16 + n16;
                bfr[ni] = *(const bf16x8*)((const char*)&sB[cur][row][0]
                          + ((ks * 64 + g * 16) ^ ((n16 & 7) << 4)));
            }
            #pragma unroll
            for (int mi = 0; mi < 2; mi++)
                #pragma unroll
                for (int ni = 0; ni < 4; ni++)
                    acc[mi][ni] = __builtin_amdgcn_mfma_f32_16x16x32_bf16(
                        af[mi], bfr[ni], acc[mi][ni], 0, 0, 0);
        }
        __syncthreads();
        cur = nxt;
    }
#undef STAGEW

    #pragma unroll
    for (int mi = 0; mi < 2; mi++) {
        #pragma unroll
        for (int ni = 0; ni < 4; ni++) {
            int col = n0 + wc * 64 + ni * 16 + n16;
            float bv = bias[col];
            #pragma unroll
            for (int r = 0; r < 4; r++) {
                int row = m0 + wr * 32 + mi * 16 + 4 * g + r;
                float val = acc[mi][ni][r] + bv;
                if (ACT == 1) val = gelu_f(val);
                if (OMODE == 1) {
                    Cb[(size_t)row * N + col] = f2bf(val);
                } else {
                    if (col < 1024) {
                        unsigned short* dst = (col < 512) ? Cb : Cbk;
                        dst[(size_t)row * 512 + (col & 511)] = f2bf(val);
                    } else {
                        Cbv[((size_t)(row >> 11) * 512 + (col - 1024)) * L_LEN + (row & (L_LEN - 1))] = f2bf(val);
                    }
                }
            }
        }
    }
}

// ---------------------------------------------------------------------------
// 64-wide bf16 MFMA GEMM (double-buffered). BM = 64, 32, or 16.
// ASRC: 0 = A via gll16; 1 = A = split-K partials (po0/po1 + pl), combined
//       in registers and ds_written to the same LDS bytes gll16 would fill.
// OMODE: 0 = f32 out, 1 = bf16 out, 2 = f32 +=, 5 = f32-residual + split-bf16
// ---------------------------------------------------------------------------
template<int ACT, int OMODE, int BM, int ASRC>
__global__ __launch_bounds__(256) void gemm_bf16(
    const unsigned short* __restrict__ A, const unsigned short* __restrict__ Wt,
    const float* __restrict__ bias, float* __restrict__ Cf,
    unsigned short* __restrict__ Cb, const float* __restrict__ pl,
    int M, int N, int Kd, int lda)
{
    __shared__ unsigned short sA[2][BM][64];
    __shared__ unsigned short sB[2][64][64];
    const int tid = threadIdx.x;
    const int l = tid & 63, w = tid >> 6;
    const int g = l >> 4, n16 = l & 15;
    const int m0 = blockIdx.y * BM, n0 = blockIdx.x * 64;

    const int r8 = l >> 3;
    const int swz8 = ((l & 7) ^ r8) * 8;

    const int NMI = (BM == 64) ? 2 : 1;
    const int NNI = (BM == 16) ? 1 : 2;
    const int wr = w >> 1;
    const int wc = w & 1;

    f32x4 acc[2][2];
    #pragma unroll
    for (int mi = 0; mi < 2; mi++)
        #pragma unroll
        for (int ni = 0; ni < 2; ni++)
            acc[mi][ni] = (f32x4){0.f, 0.f, 0.f, 0.f};

#define STAGE(buf, k0)                                                          \
    do {                                                                        \
        if (BM == 64) {                                                         \
            _Pragma("unroll")                                                   \
            for (int p = 0; p < 2; p++) {                                       \
                int row = w * 16 + p * 8 + r8;                                  \
                gll16(A + (size_t)(m0 + row) * lda + (k0) + swz8,               \
                      &sA[buf][w * 16 + p * 8][0]);                             \
            }                                                                   \
        } else if (BM == 32) {                                                  \
            int row = w * 8 + r8;                                               \
            gll16(A + (size_t)(m0 + row) * lda + (k0) + swz8,                   \
                  &sA[buf][w * 8][0]);                                          \
        } else if (ASRC == 0) {                                                 \
            if (w < 2) {                                                        \
                int row = w * 8 + r8;                                           \
                gll16(A + (size_t)(m0 + row) * lda + (k0) + swz8,               \
                      &sA[buf][w * 8][0]);                                      \
            }                                                                   \
        } else {                                                                \
            if (w < 2) {                                                        \
                int arow = w * 8 + r8;                                          \
                int hh2 = (k0) >> 6;                                            \
                float linv = 1.0f /                                             \
                    (pl[(size_t)(m0 + arow) * 8 + hh2] +                        \
                     pl[32768 + (size_t)(m0 + arow) * 8 + hh2]);                \
                const unsigned short* sp0 = A + (size_t)(m0 + arow) * lda       \
                                          + (k0) + swz8;                        \
                u16x8 a0v = *(const u16x8*)sp0;                                 \
                u16x8 a1v = *(const u16x8*)(sp0 + (size_t)4096 * 512);          \
                u16x8 cv;                                                       \
                _Pragma("unroll")                                               \
                for (int j = 0; j < 8; j++)                                     \
                    cv[j] = f2bf((bf2f((unsigned short)a0v[j])                  \
                                + bf2f((unsigned short)a1v[j])) * linv);        \
                *(u16x8*)((char*)&sA[buf][w * 8][0] + l * 16) = cv;             \
            }                                                                   \
        }                                                                       \
        _Pragma("unroll")                                                       \
        for (int p = 0; p < 2; p++) {                                           \
            int row = w * 16 + p * 8 + r8;                                      \
            gll16(Wt + (size_t)(n0 + row) * Kd + (k0) + swz8,                   \
                  &sB[buf][w * 16 + p * 8][0]);                                 \
        }                                                                       \
    } while (0)

    STAGE(0, 0);
    __syncthreads();

    int cur = 0;
    for (int k0 = 0; k0 < Kd; k0 += 64) {
        int nxt = cur ^ 1;
        if (k0 + 64 < Kd) STAGE(nxt, k0 + 64);
        #pragma unroll
        for (int ks = 0; ks < 2; ks++) {
            bf16x8 af[2], bfr[2];
            #pragma unroll
            for (int mi = 0; mi < NMI; mi++) {
                int row = (BM == 64) ? (wr * 32 + mi * 16 + n16)
                        : (BM == 32) ? (wr * 16 + n16) : n16;
                af[mi] = *(const bf16x8*)((const char*)&sA[cur][row][0]
                          + ((ks * 64 + g * 16) ^ ((n16 & 7) << 4)));
            }
            #pragma unroll
            for (int ni = 0; ni < NNI; ni++) {
                int row = (BM == 16) ? (w * 16 + n16) : (wc * 32 + ni * 16 + n16);
                bfr[ni] = *(const bf16x8*)((const char*)&sB[cur][row][0]
                          + ((ks * 64 + g * 16) ^ ((n16 & 7) << 4)));
            }
            #pragma unroll
            for (int mi = 0; mi < NMI; mi++)
                #pragma unroll
                for (int ni = 0; ni < NNI; ni++)
                    acc[mi][ni] = __builtin_amdgcn_mfma_f32_16x16x32_bf16(
                        af[mi], bfr[ni], acc[mi][ni], 0, 0, 0);
        }
        __syncthreads();
        cur = nxt;
    }
#undef STAGE

    #pragma unroll
    for (int mi = 0; mi < NMI; mi++) {
        #pragma unroll
        for (int ni = 0; ni < NNI; ni++) {
            int col = (BM == 16) ? (n0 + w * 16 + n16)
                                 : (n0 + wc * 32 + ni * 16 + n16);
            float bv = bias[col];
            #pragma unroll
            for (int r = 0; r < 4; r++) {
                int row = (BM == 64) ? (m0 + wr * 32 + mi * 16 + 4 * g + r)
                        : (BM == 32) ? (m0 + wr * 16 + 4 * g + r)
                                     : (m0 + 4 * g + r);
                float val = acc[mi][ni][r] + bv;
                if (ACT == 1) val = gelu_f(val);
                if (OMODE == 0) {
                    Cf[(size_t)row * N + col] = val;
                } else if (OMODE == 1) {
                    Cb[(size_t)row * N + col] = f2bf(val);
                } else if (OMODE == 2) {
                    float* cp = Cf + (size_t)row * N + col;
                    *cp += val;
                } else if (OMODE == 5) {
                    float xnew = Cf[(size_t)row * N + col] + val;
                    unsigned short hi = f2bf(xnew);
                    unsigned short lo = f2bf(xnew - bf2f(hi));
                    unsigned short* orow = Cb + (size_t)row * 768;
                    orow[col] = hi;
                    orow[256 + col] = lo;
                    orow[512 + col] = hi;
                }
            }
        }
    }
}

// ---------------------------------------------------------------------------
// LayerNorm: x f32 -> h bf16
// ---------------------------------------------------------------------------
__global__ __launch_bounds__(256) void ln_bf16(
    const float* __restrict__ x, const float* __restrict__ sc,
    const float* __restrict__ bi, unsigned short* __restrict__ out)
{
    int wave = threadIdx.x >> 6, lane = threadIdx.x & 63;
    int row = blockIdx.x * 4 + wave;
    const float* xr = x + (size_t)row * D_MOD;
    float4 v = *(const float4*)(xr + lane * 4);
    float s1 = v.x + v.y + v.z + v.w;
    float s2 = v.x * v.x + v.y * v.y + v.z * v.z + v.w * v.w;
    #pragma unroll
    for (int off = 1; off < 64; off <<= 1) {
        s1 += __shfl_xor(s1, off);
        s2 += __shfl_xor(s2, off);
    }
    float mean = s1 * (1.0f / 256.0f);
    float var = s2 * (1.0f / 256.0f) - mean * mean;
    float rs = rsqrtf(var + 1e-6f);
    float4 scv = *(const float4*)(sc + lane * 4);
    float4 bv  = *(const float4*)(bi + lane * 4);
    u16x4 o4;
    o4[0] = f2bf((v.x - mean) * rs * scv.x + bv.x);
    o4[1] = f2bf((v.y - mean) * rs * scv.y + bv.y);
    o4[2] = f2bf((v.z - mean) * rs * scv.z + bv.z);
    o4[3] = f2bf((v.w - mean) * rs * scv.w + bv.w);
    *(u16x4*)(out + (size_t)row * D_MOD + lane * 4) = o4;
}

// ---------------------------------------------------------------------------
// MFMA flash attention, split-K x2: grid 1024 = 4 blocks/CU. Each block does
// 16 k-tiles (half the key range) for 64 q rows of one (b,hh). Fixed-max
// softmax -> partials combine exactly. km bias via per-lane register
// fragments (coalesced). One barrier per tile. sP XOR-swizzled (no pad) so
// LDS = 40960 B -> 4 blocks/CU. Writes unnormalized bf16 o + f32 l.
// ---------------------------------------------------------------------------
__global__ __launch_bounds__(256, 4) void attn_mfma(
    const unsigned short* __restrict__ q, const unsigned short* __restrict__ k,
    const unsigned short* __restrict__ vt, const unsigned short* __restrict__ kmf,
    unsigned short* __restrict__ po, float* __restrict__ pl)
{
    __shared__ unsigned short sK[2][64][64];
    __shared__ unsigned short sV[2][64][64];    // V^T tile [d][key]
    __shared__ unsigned short sP[4][16][64];    // XOR-swizzled, no pad

    const int tid = threadIdx.x;
    const int l = tid & 63, w = tid >> 6;
    const int g = l >> 4, n16 = l & 15;

    // XCD-aware decomposition of the 1D 1024-block grid
    const int id = blockIdx.x;
    const int xcd = id & 7, rest = id >> 3;     // rest 0..127
    const int panel = xcd * 2 + (rest & 1);
    const int sub = rest >> 1;                  // 0..63
    const int half = sub & 1;
    const int qi = sub >> 1;                    // 0..31
    const int qblk = qi * 64, hh = panel & 7, b = panel >> 3;
    const int kv0 = half * 1024;

    const int r8 = l >> 3;
    const int swz8 = ((l & 7) ^ r8) * 8;

    bf16x8 qf[2];
    {
        const unsigned short* qp = q + (size_t)(b * L_LEN + qblk + w * 16 + n16) * 512 + hh * 64;
        qf[0] = *(const bf16x8*)(qp + g * 8);
        qf[1] = *(const bf16x8*)(qp + 32 + g * 8);
    }
    bf16x8 onesf;
    #pragma unroll
    for (int j = 0; j < 8; j++) onesf[j] = (short)0x3F80;

    f32x4 o_acc[4];
    #pragma unroll
    for (int c = 0; c < 4; c++) o_acc[c] = (f32x4){0.f, 0.f, 0.f, 0.f};
    f32x4 l_acc = (f32x4){0.f, 0.f, 0.f, 0.f};

    const unsigned short* kbase = k + ((size_t)(b * L_LEN) + kv0) * 512 + hh * 64;
    const unsigned short* vbase = vt + ((size_t)b * 512 + hh * 64) * L_LEN + kv0;
    const unsigned short* kmbase = kmf + (((size_t)qi * 256 + tid) * 16)
                                 + (size_t)(half * 16) * 131072;

    // ---- prologue: tile 0 ----
    #pragma unroll
    for (int p = 0; p < 2; p++) {
        int row = w * 16 + p * 8 + r8;
        gll16(kbase + (size_t)row * 512 + swz8, &sK[0][w * 16 + p * 8][0]);
        gll16(vbase + (size_t)row * L_LEN + swz8, &sV[0][w * 16 + p * 8][0]);
    }
    u16x8 kmC0 = *(const u16x8*)kmbase;
    u16x8 kmC1 = *(const u16x8*)(kmbase + 8);
    __syncthreads();

    int cur = 0;
    for (int kt = 0; kt < 16; kt++) {
        const int nb = cur ^ 1;
        const int kblk2 = (kt + 1) << 6;
        u16x8 kmN0 = kmC0, kmN1 = kmC1;
        if (kt + 1 < 16) {
            #pragma unroll
            for (int p = 0; p < 2; p++) {
                int row = w * 16 + p * 8 + r8;
                gll16(kbase + (size_t)(kblk2 + row) * 512 + swz8, &sK[nb][w * 16 + p * 8][0]);
                gll16(vbase + (size_t)row * L_LEN + kblk2 + swz8, &sV[nb][w * 16 + p * 8][0]);
            }
            const unsigned short* kp2 = kmbase + (size_t)(kt + 1) * 131072;
            kmN0 = *(const u16x8*)kp2;
            kmN1 = *(const u16x8*)(kp2 + 8);
        }
        // ---- km fragment -> MFMA C-init ----
        f32x4 sacc[4];
        #pragma unroll
        for (int c = 0; c < 4; c++)
            #pragma unroll
            for (int r = 0; r < 4; r++)
                sacc[c][r] = bf2f((unsigned short)(c < 2 ? kmC0[c * 4 + r] : kmC1[(c - 2) * 4 + r]));
        // ---- QK^T (accumulates onto km) ----
        __builtin_amdgcn_s_setprio(1);
        #pragma unroll
        for (int ks = 0; ks < 2; ks++)
            #pragma unroll
            for (int c = 0; c < 4; c++) {
                int row = c * 16 + n16;
                bf16x8 kf = *(const bf16x8*)((const char*)&sK[cur][row][0]
                             + ((ks * 64 + g * 16) ^ ((n16 & 7) << 4)));
                sacc[c] = __builtin_amdgcn_mfma_f32_16x16x32_bf16(qf[ks], kf, sacc[c], 0, 0, 0);
            }
        __builtin_amdgcn_s_setprio(0);
        // ---- p = exp2(score) ----
        float p[4][4];
        #pragma unroll
        for (int r = 0; r < 4; r++)
            #pragma unroll
            for (int c = 0; c < 4; c++)
                p[r][c] = __builtin_amdgcn_exp2f(sacc[c][r]);
        // ---- P -> per-wave LDS (bf16), XOR-swizzled cols ----
        #pragma unroll
        for (int r = 0; r < 4; r++) {
            int prow = 4 * g + r;
            #pragma unroll
            for (int c = 0; c < 4; c++)
                sP[w][prow][(c * 16 + n16) ^ ((prow & 7) << 3)] = f2bf(p[r][c]);
        }
        // ---- PV + l-sum ----
        __builtin_amdgcn_s_setprio(1);
        #pragma unroll
        for (int ks = 0; ks < 2; ks++) {
            bf16x8 pf = *(const bf16x8*)((const char*)&sP[w][n16][0]
                         + (((ks * 32 + g * 8) ^ ((n16 & 7) << 3)) * 2));
            l_acc = __builtin_amdgcn_mfma_f32_16x16x32_bf16(pf, onesf, l_acc, 0, 0, 0);
            #pragma unroll
            for (int c = 0; c < 4; c++) {
                int row = c * 16 + n16;
                bf16x8 vf = *(const bf16x8*)((const char*)&sV[cur][row][0]
                             + ((ks * 64 + g * 16) ^ ((n16 & 7) << 4)));
                o_acc[c] = __builtin_amdgcn_mfma_f32_16x16x32_bf16(pf, vf, o_acc[c], 0, 0, 0);
            }
        }
        __builtin_amdgcn_s_setprio(0);
        __syncthreads();   // single barrier: drains next-tile gll16, syncs buf reuse
        cur = nb;
        kmC0 = kmN0;
        kmC1 = kmN1;
    }

    // ---- epilogue: unnormalized partials (bf16 o, f32 l) ----
    unsigned short* pob = po + (size_t)half * (4096 * 512);
    #pragma unroll
    for (int c = 0; c < 4; c++)
        #pragma unroll
        for (int r = 0; r < 4; r++)
            pob[(size_t)(b * L_LEN + qblk + w * 16 + 4 * g + r) * 512 + hh * 64 + c * 16 + n16]
                = f2bf(o_acc[c][r]);
    if (n16 == 0) {
        #pragma unroll
        for (int r = 0; r < 4; r++)
            pl[(size_t)half * 32768 + (size_t)(b * L_LEN + qblk + w * 16 + 4 * g + r) * 8 + hh]
                = l_acc[r];
    }
}

// ---------------------------------------------------------------------------
// Fused head: out[row] = dot(gelu(xb[row] @ Whb + bh1) * Wh2) + bh2
// One block = 16 rows x 128 cols (wave w -> cols w*32..w*32+31). K=768.
// ---------------------------------------------------------------------------
__global__ __launch_bounds__(256) void head_kernel(
    const unsigned short* __restrict__ A, const unsigned short* __restrict__ Wt,
    const float* __restrict__ bh1, const float* __restrict__ Wh2,
    const float* __restrict__ bh2, float* __restrict__ out)
{
    __shared__ unsigned short sA[2][16][64];
    __shared__ unsigned short sB[2][128][64];
    __shared__ float sRed[4][16];
    const int tid = threadIdx.x;
    const int l = tid & 63, w = tid >> 6;
    const int g = l >> 4, n16 = l & 15;
    const int m0 = blockIdx.x * 16;
    const int r8 = l >> 3;
    const int swz8 = ((l & 7) ^ r8) * 8;

    f32x4 acc[2];
    acc[0] = (f32x4){0.f, 0.f, 0.f, 0.f};
    acc[1] = (f32x4){0.f, 0.f, 0.f, 0.f};

#define HSTAGE(buf, k0)                                                         \
    do {                                                                        \
        if (w < 2) {                                                            \
            int row = w * 8 + r8;                                               \
            gll16(A + (size_t)(m0 + row) * 768 + (k0) + swz8,                   \
                  &sA[buf][w * 8][0]);                                          \
        }                                                                       \
        _Pragma("unroll")                                                       \
        for (int p = 0; p < 4; p++) {                                           \
            int row = w * 32 + p * 8 + r8;                                      \
            gll16(Wt + (size_t)row * 768 + (k0) + swz8,                         \
                  &sB[buf][w * 32 + p * 8][0]);                                 \
        }                                                                       \
    } while (0)

    HSTAGE(0, 0);
    __syncthreads();

    int cur = 0;
    for (int k0 = 0; k0 < 768; k0 += 64) {
        int nxt = cur ^ 1;
        if (k0 + 64 < 768) HSTAGE(nxt, k0 + 64);
        #pragma unroll
        for (int ks = 0; ks < 2; ks++) {
            bf16x8 af = *(const bf16x8*)((const char*)&sA[cur][n16][0]
                         + ((ks * 64 + g * 16) ^ ((n16 & 7) << 4)));
            #pragma unroll
            for (int ni = 0; ni < 2; ni++) {
                int row = w * 32 + ni * 16 + n16;
                bf16x8 bfr = *(const bf16x8*)((const char*)&sB[cur][row][0]
                              + ((ks * 64 + g * 16) ^ ((n16 & 7) << 4)));
                acc[ni] = __builtin_amdgcn_mfma_f32_16x16x32_bf16(af, bfr, acc[ni], 0, 0, 0);
            }
        }
        __syncthreads();
        cur = nxt;
    }
#undef HSTAGE

    float s[4];
    #pragma unroll
    for (int r = 0; r < 4; r++) {
        s[r] = 0.f;
        #pragma unroll
        for (int ni = 0; ni < 2; ni++) {
            int col = w * 32 + ni * 16 + n16;
            s[r] += gelu_f(acc[ni][r] + bh1[col]) * Wh2[col];
        }
        s[r] += __shfl_xor(s[r], 1);
        s[r] += __shfl_xor(s[r], 2);
        s[r] += __shfl_xor(s[r], 4);
        s[r] += __shfl_xor(s[r], 8);
    }
    if (n16 == 0) {
        #pragma unroll
        for (int r = 0; r < 4; r++) sRed[w][4 * g + r] = s[r];
    }
    __syncthreads();
    if (tid < 16)
        out[m0 + tid] = sRed[0][tid] + sRed[1][tid] + sRed[2][tid] + sRed[3][tid] + bh2[0];
}

// ---------------------------------------------------------------------------
extern "C" void kernel_launch(void* const* d_in, const int* in_sizes, int n_in,
                              void* d_out, int out_size, void* d_ws, size_t ws_size,
                              hipStream_t stream)
{
    const float* z      = (const float*)d_in[0];
    const float* cond   = (const float*)d_in[1];
    const float* s      = (const float*)d_in[2];
    const float* Kmat   = (const float*)d_in[3];
    const float* embed  = (const float*)d_in[4];
    const float* W_in1  = (const float*)d_in[5];
    const float* b_in1  = (const float*)d_in[6];
    const float* W_in2  = (const float*)d_in[7];
    const float* b_in2  = (const float*)d_in[8];
    const float* bias_w = (const float*)d_in[9];
    const float* bias_b = (const float*)d_in[10];  // cancels in softmax
    const float* Wq     = (const float*)d_in[11];
    const float* bq     = (const float*)d_in[12];
    const float* Wk     = (const float*)d_in[13];
    const float* bk     = (const float*)d_in[14];
    const float* Wv     = (const float*)d_in[15];
    const float* bv     = (const float*)d_in[16];
    const float* Wo     = (const float*)d_in[17];
    const float* bo     = (const float*)d_in[18];
    const float* ln1_s  = (const float*)d_in[19];
    const float* ln1_b  = (const float*)d_in[20];
    const float* ln2_s  = (const float*)d_in[21];
    const float* ln2_b  = (const float*)d_in[22];
    const float* Wf1    = (const float*)d_in[23];
    const float* bf1    = (const float*)d_in[24];
    const float* Wf2    = (const float*)d_in[25];
    const float* bf2    = (const float*)d_in[26];
    const float* Wh1    = (const float*)d_in[27];
    const float* bh1    = (const float*)d_in[28];
    const float* Wh2    = (const float*)d_in[29];
    const float* bh2    = (const float*)d_in[30];
    float* out = (float*)d_out;
    (void)bias_b;

    const int M = B_SZ * L_LEN; // 4096
    char* base = (char*)d_ws;
    unsigned short* feats = (unsigned short*)base;                     // 4096*576 bf16
    float* x = (float*)(base + (size_t)M * FIN_PAD * 2);               // 4096*256 f32
    unsigned short* h    = (unsigned short*)((char*)x + (size_t)M * D_MOD * 4);
    unsigned short* hid1 = h    + (size_t)M * D_MOD;                   // 4096*1024
    unsigned short* qb   = hid1 + (size_t)M * 1024;                    // 4096*512 (also head xb [4096][768] with kb2)
    unsigned short* kb2  = qb   + (size_t)M * 512;
    unsigned short* vtb  = kb2  + (size_t)M * 512;                     // [2][512][2048]
    unsigned short* ob   = vtb  + (size_t)M * 512;
    unsigned short* wt   = ob   + (size_t)M * 512;                     // WT_END elems
    float* bqkv          = (float*)(wt + WT_END);                      // 2*1536 f32
    unsigned short* kmfrag = (unsigned short*)(bqkv + 2 * 1536);       // [2][1<<22]
    unsigned short* po   = kmfrag + ((size_t)2 << 22);                 // [2][4096][512] bf16
    float* pl            = (float*)(po + (size_t)2 * 4096 * 512);      // [2][4096][8] f32
    (void)ob;

    prep_kernel<<<dim3(3292), dim3(256), 0, stream>>>(
        W_in1, W_in2, Wq, Wk, Wv, Wo, Wf1, Wf2, Wh1, Kmat, bias_w,
        bq, bk, bv, z, s, embed, cond, wt, kmfrag, bqkv, feats);

    gemmW<1, 1><<<dim3(8, 64), 256, 0, stream>>>(feats, wt + OFF_IN1, b_in1, hid1, nullptr, nullptr, M, 1024, FIN_PAD, FIN_PAD);
    gemm_bf16<0, 0, 16, 0><<<dim3(4, 256), 256, 0, stream>>>(hid1, wt + OFF_IN2, b_in2, x, nullptr, nullptr, M, 256, 1024, 1024);

    for (int i = 0; i < NB_BLK; i++) {
        ln_bf16<<<dim3(M / 4), 256, 0, stream>>>(x, ln1_s + i * D_MOD, ln1_b + i * D_MOD, h);
        gemmW<0, 4><<<dim3(12, 64), 256, 0, stream>>>(h, wt + OFF_QKV + (size_t)i * 393216, bqkv + i * 1536, qb, kb2, vtb, M, 1536, 256, 256);
        attn_mfma<<<dim3(1024), 256, 0, stream>>>(qb, kb2, vtb, kmfrag + ((size_t)i << 22), po, pl);
        gemm_bf16<0, 2, 16, 1><<<dim3(4, 256), 256, 0, stream>>>(po, wt + OFF_O + (size_t)i * 131072, bo + i * D_MOD, x, nullptr, pl, M, 256, 512, 512);
        ln_bf16<<<dim3(M / 4), 256, 0, stream>>>(x, ln2_s + i * D_MOD, ln2_b + i * D_MOD, h);
        gemmW<1, 1><<<dim3(8, 64), 256, 0, stream>>>(h, wt + OFF_F1 + (size_t)i * 262144, bf1 + i * 1024, hid1, nullptr, nullptr, M, 1024, 256, 256);
        if (i == 0)
            gemm_bf16<0, 2, 16, 0><<<dim3(4, 256), 256, 0, stream>>>(hid1, wt + OFF_F2 + (size_t)i * 262144, bf2 + i * D_MOD, x, nullptr, nullptr, M, 256, 1024, 1024);
        else
            gemm_bf16<0, 5, 16, 0><<<dim3(4, 256), 256, 0, stream>>>(hid1, wt + OFF_F2 + (size_t)i * 262144, bf2 + i * D_MOD, x, qb, nullptr, M, 256, 1024, 1024);
    }
    head_kernel<<<dim3(256), 256, 0, stream>>>(qb, wt + OFF_H, bh1, Wh2, bh2, out);
}

// Round 18
// 225.279 us; speedup vs baseline: 1.0003x; 1.0003x over previous
//
#include <hip/hip_runtime.h>
#include <math.h>

#define B_SZ 2
#define L_LEN 2048
#define D_MOD 256
#define H_HEADS 8
#define NB_BLK 2
#define S_SZ 2
#define E_SZ 503
#define C_SZ 8
#define FIN 514
#define FIN_PAD 576
#define LOG2E 1.44269504088896340736f
#define QSC (0.125f * LOG2E)

typedef short bf16x8 __attribute__((ext_vector_type(8)));
typedef float f32x4 __attribute__((ext_vector_type(4)));
typedef unsigned short u16x4 __attribute__((ext_vector_type(4)));
typedef unsigned short u16x8 __attribute__((ext_vector_type(8)));

// bf16 weight buffer offsets (elements) inside wt
#define OFF_IN1 0           // [1024][576]
#define OFF_IN2 589824      // [256][1024]
#define OFF_QKV 851968      // [2][1536][256]  rows: 0-511 q(*QSC), 512-1023 k, 1024-1535 v
#define OFF_O   1638400     // [2][256][512]
#define OFF_F1  1900544     // [2][1024][256]
#define OFF_F2  2424832     // [2][256][1024]
#define OFF_H   2949120     // [128][768]  (Whi | Whi | Wlo)
#define WT_END  3047424

__device__ __forceinline__ unsigned short f2bf(float x) {
    unsigned u = __float_as_uint(x);
    u += 0x7FFFu + ((u >> 16) & 1u);
    return (unsigned short)(u >> 16);
}

__device__ __forceinline__ float bf2f(unsigned short h) {
    return __uint_as_float(((unsigned)h) << 16);
}

__device__ __forceinline__ float gelu_f(float x) {
    float x3 = x * x * x;
    return 0.5f * x * (1.0f + tanhf(0.7978845608028654f * (x + 0.044715f * x3)));
}

__device__ __forceinline__ void gll16(const void* g, void* l) {
    __builtin_amdgcn_global_load_lds(
        (const __attribute__((address_space(1))) unsigned int*)g,
        (__attribute__((address_space(3))) unsigned int*)l,
        16, 0, 0);
}

// ---------------------------------------------------------------------------
// Merged prep: [0,720) wprep | [720,1104) hprep | [1104,2128) km_frag (both i)
// | [2128,2140) bprep | [2140,3292) feats (both b, 4 elems/thread)
// km_frag layout: [i][kt*32+qb][lane 0..255][16 bf16]
// value[c*4+r] = LOG2E*bias_w[i]*Kmat[qb*64+16w+4g+r][kt*64+c*16+n16]
// ---------------------------------------------------------------------------
__global__ __launch_bounds__(256) void prep_kernel(
    const float* __restrict__ W_in1, const float* __restrict__ W_in2,
    const float* __restrict__ Wq, const float* __restrict__ Wk,
    const float* __restrict__ Wv, const float* __restrict__ Wo,
    const float* __restrict__ Wf1, const float* __restrict__ Wf2,
    const float* __restrict__ Wh1, const float* __restrict__ Kmat,
    const float* __restrict__ bias_w,
    const float* __restrict__ bq, const float* __restrict__ bk,
    const float* __restrict__ bv,
    const float* __restrict__ z, const float* __restrict__ s,
    const float* __restrict__ embed, const float* __restrict__ cond,
    unsigned short* __restrict__ wt, unsigned short* __restrict__ kmfrag,
    float* __restrict__ bqkv, unsigned short* __restrict__ feats)
{
    __shared__ unsigned short sT[64][65];
    int b = blockIdx.x;
    int t = threadIdx.x;

    if (b < 720) {
        // ---- weight transpose+cast ----
        const float* src; unsigned short* dst; int K, N, Kp, tile;
        float scale = 1.0f;
        if (b < 144)      { src = W_in1; dst = wt + OFF_IN1; K = 514;  N = 1024; Kp = 576;  tile = b; }
        else if (b < 208) { src = W_in2; dst = wt + OFF_IN2; K = 1024; N = 256;  Kp = 1024; tile = b - 144; }
        else if (b < 400) { int t2 = b - 208;
                            int sec = t2 >> 5; tile = t2 & 31;
                            int i = sec / 3, which = sec % 3;
                            const float* wsrc = which == 0 ? Wq : which == 1 ? Wk : Wv;
                            if (which == 0) scale = QSC;
                            src = wsrc + (size_t)i * 131072;
                            dst = wt + OFF_QKV + (size_t)i * 393216 + (size_t)which * 131072;
                            K = 256; N = 512; Kp = 256; }
        else if (b < 464) { int t2 = b - 400; int i = t2 >> 5; tile = t2 & 31;
                            src = Wo + (size_t)i * 131072; dst = wt + OFF_O + (size_t)i * 131072;
                            K = 512; N = 256; Kp = 512; }
        else if (b < 592) { int t2 = b - 464; int i = t2 >> 6; tile = t2 & 63;
                            src = Wf1 + (size_t)i * 262144; dst = wt + OFF_F1 + (size_t)i * 262144;
                            K = 256; N = 1024; Kp = 256; }
        else              { int t2 = b - 592; int i = t2 >> 6; tile = t2 & 63;
                            src = Wf2 + (size_t)i * 262144; dst = wt + OFF_F2 + (size_t)i * 262144;
                            K = 1024; N = 256; Kp = 1024; }

        int nt = N >> 6;
        int kt0 = (tile / nt) << 6;
        int nt0 = (tile % nt) << 6;
        #pragma unroll
        for (int p = 0; p < 4; p++) {
            int r = p * 16 + (t >> 4);
            int c = (t & 15) * 4;
            float4 v4 = make_float4(0.f, 0.f, 0.f, 0.f);
            if (kt0 + r < K) v4 = *(const float4*)(src + (size_t)(kt0 + r) * N + nt0 + c);
            sT[r][c + 0] = f2bf(v4.x * scale);
            sT[r][c + 1] = f2bf(v4.y * scale);
            sT[r][c + 2] = f2bf(v4.z * scale);
            sT[r][c + 3] = f2bf(v4.w * scale);
        }
        __syncthreads();
        int n = t >> 2, kq = (t & 3) * 16;
        u16x8 o0, o1;
        #pragma unroll
        for (int j = 0; j < 8; j++) {
            o0[j] = sT[kq + j][n];
            o1[j] = sT[kq + 8 + j][n];
        }
        unsigned short* dp = dst + (size_t)(nt0 + n) * Kp + kt0 + kq;
        *(u16x8*)(dp) = o0;
        *(u16x8*)(dp + 8) = o1;
    } else if (b < 1104) {
        // ---- head split-precision weights ----
        int idx = (b - 720) * 256 + t;   // 128*768
        if (idx < 128 * 768) {
            int n = idx / 768, kk = idx % 768;
            int kz = kk & 255;
            float v = Wh1[(size_t)kz * 128 + n];
            unsigned short hi = f2bf(v);
            wt[OFF_H + idx] = (kk < 512) ? hi : f2bf(v - bf2f(hi));
        }
    } else if (b < 2128) {
        // ---- km_frag: per-lane attention bias fragments, BOTH layers ----
        int tile = b - 1104;               // [0,1024)
        int kt = tile >> 5, qb = tile & 31;
        float s0 = bias_w[0] * LOG2E, s1 = bias_w[1] * LOG2E;
        int q0 = qb * 64 + ((t >> 6) << 4) + (((t >> 4) & 3) << 2);
        int k0 = kt * 64 + (t & 15);
        u16x8 a0, a1, b0, b1;
        #pragma unroll
        for (int c = 0; c < 4; c++)
            #pragma unroll
            for (int r = 0; r < 4; r++) {
                float v = Kmat[(size_t)(q0 + r) * L_LEN + k0 + c * 16];
                if (c < 2) { a0[c * 4 + r] = f2bf(v * s0); b0[c * 4 + r] = f2bf(v * s1); }
                else       { a1[(c - 2) * 4 + r] = f2bf(v * s0); b1[(c - 2) * 4 + r] = f2bf(v * s1); }
            }
        unsigned short* dp = kmfrag + (((size_t)(kt * 32 + qb)) * 256 + t) * 16;
        *(u16x8*)dp = a0;
        *(u16x8*)(dp + 8) = a1;
        unsigned short* dp1 = dp + ((size_t)1 << 22);
        *(u16x8*)dp1 = b0;
        *(u16x8*)(dp1 + 8) = b1;
    } else if (b < 2140) {
        // ---- fused QKV bias ----
        int idx = (b - 2128) * 256 + t;
        if (idx < 2 * 1536) {
            int i = idx / 1536, c = idx % 1536;
            float v;
            if (c < 512)       v = bq[i * 512 + c] * QSC;
            else if (c < 1024) v = bk[i * 512 + c - 512];
            else               v = bv[i * 512 + c - 1024];
            bqkv[idx] = v;
        }
    } else {
        // ---- feats: 4 elems/thread, both b rows from one read ----
        int idx = (b - 2140) * 256 + t;    // [0, 294912)
        int l = idx / 144;
        int f0 = (idx % 144) * 4;
        u16x4 pk0, pk1;
        #pragma unroll
        for (int j = 0; j < 4; j++) {
            int f = f0 + j;
            float val;
            if (f >= 3 && f < 506)      val = embed[(size_t)l * E_SZ + (f - 3)];
            else if (f >= 1 && f < 3)   val = s[l * S_SZ + (f - 1)];
            else if (f >= 506 && f < FIN) val = cond[f - 506];
            else                        val = 0.0f;
            unsigned short hv = f2bf(val);
            pk0[j] = (f == 0) ? f2bf(z[l]) : hv;
            pk1[j] = (f == 0) ? f2bf(z[L_LEN + l]) : hv;
        }
        *(u16x4*)(feats + (size_t)l * FIN_PAD + f0) = pk0;
        *(u16x4*)(feats + (size_t)(L_LEN + l) * FIN_PAD + f0) = pk1;
    }
}

// ---------------------------------------------------------------------------
// Wide-tile bf16 MFMA GEMM: 64x128 per block, 4 waves each 32x64 (2x4 frags),
// gll16 staging + XOR-swizzled LDS, double-buffered.
// OMODE: 1 = bf16 out, 4 = fused QKV routing
// ---------------------------------------------------------------------------
template<int ACT, int OMODE>
__global__ __launch_bounds__(256) void gemmW(
    const unsigned short* __restrict__ A, const unsigned short* __restrict__ Wt,
    const float* __restrict__ bias, unsigned short* __restrict__ Cb,
    unsigned short* __restrict__ Cbk, unsigned short* __restrict__ Cbv,
    int M, int N, int Kd, int lda)
{
    __shared__ unsigned short sA[2][64][64];
    __shared__ unsigned short sB[2][128][64];
    const int tid = threadIdx.x;
    const int l = tid & 63, w = tid >> 6;
    const int g = l >> 4, n16 = l & 15;
    const int wr = w >> 1, wc = w & 1;
    const int m0 = blockIdx.y * 64, n0 = blockIdx.x * 128;
    const int r8 = l >> 3;
    const int swz8 = ((l & 7) ^ r8) * 8;

    f32x4 acc[2][4];
    #pragma unroll
    for (int mi = 0; mi < 2; mi++)
        #pragma unroll
        for (int ni = 0; ni < 4; ni++)
            acc[mi][ni] = (f32x4){0.f, 0.f, 0.f, 0.f};

#define STAGEW(buf, k0)                                                         \
    do {                                                                        \
        _Pragma("unroll")                                                       \
        for (int p = 0; p < 2; p++) {                                           \
            int row = w * 16 + p * 8 + r8;                                      \
            gll16(A + (size_t)(m0 + row) * lda + (k0) + swz8,                   \
                  &sA[buf][w * 16 + p * 8][0]);                                 \
        }                                                                       \
        _Pragma("unroll")                                                       \
        for (int p = 0; p < 4; p++) {                                           \
            int row = w * 32 + p * 8 + r8;                                      \
            gll16(Wt + (size_t)(n0 + row) * Kd + (k0) + swz8,                   \
                  &sB[buf][w * 32 + p * 8][0]);                                 \
        }                                                                       \
    } while (0)

    STAGEW(0, 0);
    __syncthreads();

    int cur = 0;
    for (int k0 = 0; k0 < Kd; k0 += 64) {
        int nxt = cur ^ 1;
        if (k0 + 64 < Kd) STAGEW(nxt, k0 + 64);
        #pragma unroll
        for (int ks = 0; ks < 2; ks++) {
            bf16x8 af[2], bfr[4];
            #pragma unroll
            for (int mi = 0; mi < 2; mi++) {
                int row = wr * 32 + mi * 16 + n16;
                af[mi] = *(const bf16x8*)((const char*)&sA[cur][row][0]
                          + ((ks * 64 + g * 16) ^ ((n16 & 7) << 4)));
            }
            #pragma unroll
            for (int ni = 0; ni < 4; ni++) {
                int row = wc * 64 + ni * 16 + n16;
                bfr[ni] = *(const bf16x8*)((const char*)&sB[cur][row][0]
                          + ((ks * 64 + g * 16) ^ ((n16 & 7) << 4)));
            }
            #pragma unroll
            for (int mi = 0; mi < 2; mi++)
                #pragma unroll
                for (int ni = 0; ni < 4; ni++)
                    acc[mi][ni] = __builtin_amdgcn_mfma_f32_16x16x32_bf16(
                        af[mi], bfr[ni], acc[mi][ni], 0, 0, 0);
        }
        __syncthreads();
        cur = nxt;
    }
#undef STAGEW

    #pragma unroll
    for (int mi = 0; mi < 2; mi++) {
        #pragma unroll
        for (int ni = 0; ni < 4; ni++) {
            int col = n0 + wc * 64 + ni * 16 + n16;
            float bv = bias[col];
            #pragma unroll
            for (int r = 0; r < 4; r++) {
                int row = m0 + wr * 32 + mi * 16 + 4 * g + r;
                float val = acc[mi][ni][r] + bv;
                if (ACT == 1) val = gelu_f(val);
                if (OMODE == 1) {
                    Cb[(size_t)row * N + col] = f2bf(val);
                } else {
                    if (col < 1024) {
                        unsigned short* dst = (col < 512) ? Cb : Cbk;
                        dst[(size_t)row * 512 + (col & 511)] = f2bf(val);
                    } else {
                        Cbv[((size_t)(row >> 11) * 512 + (col - 1024)) * L_LEN + (row & (L_LEN - 1))] = f2bf(val);
                    }
                }
            }
        }
    }
}

// ---------------------------------------------------------------------------
// 64-wide bf16 MFMA GEMM (double-buffered). BM = 64, 32, or 16.
// ASRC: 0 = A via gll16; 1 = A = split-K partials (po0/po1 + pl), combined
//       in registers and ds_written to the same LDS bytes gll16 would fill.
// OMODE: 0 = f32 out, 1 = bf16 out, 2 = f32 +=, 5 = f32-residual + split-bf16
// ---------------------------------------------------------------------------
template<int ACT, int OMODE, int BM, int ASRC>
__global__ __launch_bounds__(256) void gemm_bf16(
    const unsigned short* __restrict__ A, const unsigned short* __restrict__ Wt,
    const float* __restrict__ bias, float* __restrict__ Cf,
    unsigned short* __restrict__ Cb, const float* __restrict__ pl,
    int M, int N, int Kd, int lda)
{
    __shared__ unsigned short sA[2][BM][64];
    __shared__ unsigned short sB[2][64][64];
    const int tid = threadIdx.x;
    const int l = tid & 63, w = tid >> 6;
    const int g = l >> 4, n16 = l & 15;
    const int m0 = blockIdx.y * BM, n0 = blockIdx.x * 64;

    const int r8 = l >> 3;
    const int swz8 = ((l & 7) ^ r8) * 8;

    const int NMI = (BM == 64) ? 2 : 1;
    const int NNI = (BM == 16) ? 1 : 2;
    const int wr = w >> 1;
    const int wc = w & 1;

    f32x4 acc[2][2];
    #pragma unroll
    for (int mi = 0; mi < 2; mi++)
        #pragma unroll
        for (int ni = 0; ni < 2; ni++)
            acc[mi][ni] = (f32x4){0.f, 0.f, 0.f, 0.f};

#define STAGE(buf, k0)                                                          \
    do {                                                                        \
        if (BM == 64) {                                                         \
            _Pragma("unroll")                                                   \
            for (int p = 0; p < 2; p++) {                                       \
                int row = w * 16 + p * 8 + r8;                                  \
                gll16(A + (size_t)(m0 + row) * lda + (k0) + swz8,               \
                      &sA[buf][w * 16 + p * 8][0]);                             \
            }                                                                   \
        } else if (BM == 32) {                                                  \
            int row = w * 8 + r8;                                               \
            gll16(A + (size_t)(m0 + row) * lda + (k0) + swz8,                   \
                  &sA[buf][w * 8][0]);                                          \
        } else if (ASRC == 0) {                                                 \
            if (w < 2) {                                                        \
                int row = w * 8 + r8;                                           \
                gll16(A + (size_t)(m0 + row) * lda + (k0) + swz8,               \
                      &sA[buf][w * 8][0]);                                      \
            }                                                                   \
        } else {                                                                \
            if (w < 2) {                                                        \
                int arow = w * 8 + r8;                                          \
                int hh2 = (k0) >> 6;                                            \
                float linv = 1.0f /                                             \
                    (pl[(size_t)(m0 + arow) * 8 + hh2] +                        \
                     pl[32768 + (size_t)(m0 + arow) * 8 + hh2]);                \
                const unsigned short* sp0 = A + (size_t)(m0 + arow) * lda       \
                                          + (k0) + swz8;                        \
                u16x8 a0v = *(const u16x8*)sp0;                                 \
                u16x8 a1v = *(const u16x8*)(sp0 + (size_t)4096 * 512);          \
                u16x8 cv;                                                       \
                _Pragma("unroll")                                               \
                for (int j = 0; j < 8; j++)                                     \
                    cv[j] = f2bf((bf2f((unsigned short)a0v[j])                  \
                                + bf2f((unsigned short)a1v[j])) * linv);        \
                *(u16x8*)((char*)&sA[buf][w * 8][0] + l * 16) = cv;             \
            }                                                                   \
        }                                                                       \
        _Pragma("unroll")                                                       \
        for (int p = 0; p < 2; p++) {                                           \
            int row = w * 16 + p * 8 + r8;                                      \
            gll16(Wt + (size_t)(n0 + row) * Kd + (k0) + swz8,                   \
                  &sB[buf][w * 16 + p * 8][0]);                                 \
        }                                                                       \
    } while (0)

    STAGE(0, 0);
    __syncthreads();

    int cur = 0;
    for (int k0 = 0; k0 < Kd; k0 += 64) {
        int nxt = cur ^ 1;
        if (k0 + 64 < Kd) STAGE(nxt, k0 + 64);
        #pragma unroll
        for (int ks = 0; ks < 2; ks++) {
            bf16x8 af[2], bfr[2];
            #pragma unroll
            for (int mi = 0; mi < NMI; mi++) {
                int row = (BM == 64) ? (wr * 32 + mi * 16 + n16)
                        : (BM == 32) ? (wr * 16 + n16) : n16;
                af[mi] = *(const bf16x8*)((const char*)&sA[cur][row][0]
                          + ((ks * 64 + g * 16) ^ ((n16 & 7) << 4)));
            }
            #pragma unroll
            for (int ni = 0; ni < NNI; ni++) {
                int row = (BM == 16) ? (w * 16 + n16) : (wc * 32 + ni * 16 + n16);
                bfr[ni] = *(const bf16x8*)((const char*)&sB[cur][row][0]
                          + ((ks * 64 + g * 16) ^ ((n16 & 7) << 4)));
            }
            #pragma unroll
            for (int mi = 0; mi < NMI; mi++)
                #pragma unroll
                for (int ni = 0; ni < NNI; ni++)
                    acc[mi][ni] = __builtin_amdgcn_mfma_f32_16x16x32_bf16(
                        af[mi], bfr[ni], acc[mi][ni], 0, 0, 0);
        }
        __syncthreads();
        cur = nxt;
    }
#undef STAGE

    #pragma unroll
    for (int mi = 0; mi < NMI; mi++) {
        #pragma unroll
        for (int ni = 0; ni < NNI; ni++) {
            int col = (BM == 16) ? (n0 + w * 16 + n16)
                                 : (n0 + wc * 32 + ni * 16 + n16);
            float bv = bias[col];
            #pragma unroll
            for (int r = 0; r < 4; r++) {
                int row = (BM == 64) ? (m0 + wr * 32 + mi * 16 + 4 * g + r)
                        : (BM == 32) ? (m0 + wr * 16 + 4 * g + r)
                                     : (m0 + 4 * g + r);
                float val = acc[mi][ni][r] + bv;
                if (ACT == 1) val = gelu_f(val);
                if (OMODE == 0) {
                    Cf[(size_t)row * N + col] = val;
                } else if (OMODE == 1) {
                    Cb[(size_t)row * N + col] = f2bf(val);
                } else if (OMODE == 2) {
                    float* cp = Cf + (size_t)row * N + col;
                    *cp += val;
                } else if (OMODE == 5) {
                    float xnew = Cf[(size_t)row * N + col] + val;
                    unsigned short hi = f2bf(xnew);
                    unsigned short lo = f2bf(xnew - bf2f(hi));
                    unsigned short* orow = Cb + (size_t)row * 768;
                    orow[col] = hi;
                    orow[256 + col] = lo;
                    orow[512 + col] = hi;
                }
            }
        }
    }
}

// ---------------------------------------------------------------------------
// LayerNorm: x f32 -> h bf16
// ---------------------------------------------------------------------------
__global__ __launch_bounds__(256) void ln_bf16(
    const float* __restrict__ x, const float* __restrict__ sc,
    const float* __restrict__ bi, unsigned short* __restrict__ out)
{
    int wave = threadIdx.x >> 6, lane = threadIdx.x & 63;
    int row = blockIdx.x * 4 + wave;
    const float* xr = x + (size_t)row * D_MOD;
    float4 v = *(const float4*)(xr + lane * 4);
    float s1 = v.x + v.y + v.z + v.w;
    float s2 = v.x * v.x + v.y * v.y + v.z * v.z + v.w * v.w;
    #pragma unroll
    for (int off = 1; off < 64; off <<= 1) {
        s1 += __shfl_xor(s1, off);
        s2 += __shfl_xor(s2, off);
    }
    float mean = s1 * (1.0f / 256.0f);
    float var = s2 * (1.0f / 256.0f) - mean * mean;
    float rs = rsqrtf(var + 1e-6f);
    float4 scv = *(const float4*)(sc + lane * 4);
    float4 bv  = *(const float4*)(bi + lane * 4);
    u16x4 o4;
    o4[0] = f2bf((v.x - mean) * rs * scv.x + bv.x);
    o4[1] = f2bf((v.y - mean) * rs * scv.y + bv.y);
    o4[2] = f2bf((v.z - mean) * rs * scv.z + bv.z);
    o4[3] = f2bf((v.w - mean) * rs * scv.w + bv.w);
    *(u16x4*)(out + (size_t)row * D_MOD + lane * 4) = o4;
}

// ---------------------------------------------------------------------------
// MFMA flash attention, split-K x2: grid 1024 = 4 blocks/CU. Each block does
// 16 k-tiles (half the key range) for 64 q rows of one (b,hh). Fixed-max
// softmax -> partials combine exactly. km bias via per-lane register
// fragments (coalesced). One barrier per tile. sP XOR-swizzled (no pad) so
// LDS = 40960 B -> 4 blocks/CU. Writes unnormalized bf16 o + f32 l.
// ---------------------------------------------------------------------------
__global__ __launch_bounds__(256, 4) void attn_mfma(
    const unsigned short* __restrict__ q, const unsigned short* __restrict__ k,
    const unsigned short* __restrict__ vt, const unsigned short* __restrict__ kmf,
    unsigned short* __restrict__ po, float* __restrict__ pl)
{
    __shared__ unsigned short sK[2][64][64];
    __shared__ unsigned short sV[2][64][64];    // V^T tile [d][key]
    __shared__ unsigned short sP[4][16][64];    // XOR-swizzled, no pad

    const int tid = threadIdx.x;
    const int l = tid & 63, w = tid >> 6;
    const int g = l >> 4, n16 = l & 15;

    // XCD-aware decomposition of the 1D 1024-block grid
    const int id = blockIdx.x;
    const int xcd = id & 7, rest = id >> 3;     // rest 0..127
    const int panel = xcd * 2 + (rest & 1);
    const int sub = rest >> 1;                  // 0..63
    const int half = sub & 1;
    const int qi = sub >> 1;                    // 0..31
    const int qblk = qi * 64, hh = panel & 7, b = panel >> 3;
    const int kv0 = half * 1024;

    const int r8 = l >> 3;
    const int swz8 = ((l & 7) ^ r8) * 8;

    bf16x8 qf[2];
    {
        const unsigned short* qp = q + (size_t)(b * L_LEN + qblk + w * 16 + n16) * 512 + hh * 64;
        qf[0] = *(const bf16x8*)(qp + g * 8);
        qf[1] = *(const bf16x8*)(qp + 32 + g * 8);
    }
    bf16x8 onesf;
    #pragma unroll
    for (int j = 0; j < 8; j++) onesf[j] = (short)0x3F80;

    f32x4 o_acc[4];
    #pragma unroll
    for (int c = 0; c < 4; c++) o_acc[c] = (f32x4){0.f, 0.f, 0.f, 0.f};
    f32x4 l_acc = (f32x4){0.f, 0.f, 0.f, 0.f};

    const unsigned short* kbase = k + ((size_t)(b * L_LEN) + kv0) * 512 + hh * 64;
    const unsigned short* vbase = vt + ((size_t)b * 512 + hh * 64) * L_LEN + kv0;
    const unsigned short* kmbase = kmf + (((size_t)qi * 256 + tid) * 16)
                                 + (size_t)(half * 16) * 131072;

    // ---- prologue: tile 0 ----
    #pragma unroll
    for (int p = 0; p < 2; p++) {
        int row = w * 16 + p * 8 + r8;
        gll16(kbase + (size_t)row * 512 + swz8, &sK[0][w * 16 + p * 8][0]);
        gll16(vbase + (size_t)row * L_LEN + swz8, &sV[0][w * 16 + p * 8][0]);
    }
    u16x8 kmC0 = *(const u16x8*)kmbase;
    u16x8 kmC1 = *(const u16x8*)(kmbase + 8);
    __syncthreads();

    int cur = 0;
    for (int kt = 0; kt < 16; kt++) {
        const int nb = cur ^ 1;
        const int kblk2 = (kt + 1) << 6;
        u16x8 kmN0 = kmC0, kmN1 = kmC1;
        if (kt + 1 < 16) {
            #pragma unroll
            for (int p = 0; p < 2; p++) {
                int row = w * 16 + p * 8 + r8;
                gll16(kbase + (size_t)(kblk2 + row) * 512 + swz8, &sK[nb][w * 16 + p * 8][0]);
                gll16(vbase + (size_t)row * L_LEN + kblk2 + swz8, &sV[nb][w * 16 + p * 8][0]);
            }
            const unsigned short* kp2 = kmbase + (size_t)(kt + 1) * 131072;
            kmN0 = *(const u16x8*)kp2;
            kmN1 = *(const u16x8*)(kp2 + 8);
        }
        // ---- km fragment -> MFMA C-init ----
        f32x4 sacc[4];
        #pragma unroll
        for (int c = 0; c < 4; c++)
            #pragma unroll
            for (int r = 0; r < 4; r++)
                sacc[c][r] = bf2f((unsigned short)(c < 2 ? kmC0[c * 4 + r] : kmC1[(c - 2) * 4 + r]));
        // ---- QK^T (accumulates onto km) ----
        __builtin_amdgcn_s_setprio(1);
        #pragma unroll
        for (int ks = 0; ks < 2; ks++)
            #pragma unroll
            for (int c = 0; c < 4; c++) {
                int row = c * 16 + n16;
                bf16x8 kf = *(const bf16x8*)((const char*)&sK[cur][row][0]
                             + ((ks * 64 + g * 16) ^ ((n16 & 7) << 4)));
                sacc[c] = __builtin_amdgcn_mfma_f32_16x16x32_bf16(qf[ks], kf, sacc[c], 0, 0, 0);
            }
        __builtin_amdgcn_s_setprio(0);
        // ---- p = exp2(score) ----
        float p[4][4];
        #pragma unroll
        for (int r = 0; r < 4; r++)
            #pragma unroll
            for (int c = 0; c < 4; c++)
                p[r][c] = __builtin_amdgcn_exp2f(sacc[c][r]);
        // ---- P -> per-wave LDS (bf16), XOR-swizzled cols ----
        #pragma unroll
        for (int r = 0; r < 4; r++) {
            int prow = 4 * g + r;
            #pragma unroll
            for (int c = 0; c < 4; c++)
                sP[w][prow][(c * 16 + n16) ^ ((prow & 7) << 3)] = f2bf(p[r][c]);
        }
        // ---- PV + l-sum ----
        __builtin_amdgcn_s_setprio(1);
        #pragma unroll
        for (int ks = 0; ks < 2; ks++) {
            bf16x8 pf = *(const bf16x8*)((const char*)&sP[w][n16][0]
                         + (((ks * 32 + g * 8) ^ ((n16 & 7) << 3)) * 2));
            l_acc = __builtin_amdgcn_mfma_f32_16x16x32_bf16(pf, onesf, l_acc, 0, 0, 0);
            #pragma unroll
            for (int c = 0; c < 4; c++) {
                int row = c * 16 + n16;
                bf16x8 vf = *(const bf16x8*)((const char*)&sV[cur][row][0]
                             + ((ks * 64 + g * 16) ^ ((n16 & 7) << 4)));
                o_acc[c] = __builtin_amdgcn_mfma_f32_16x16x32_bf16(pf, vf, o_acc[c], 0, 0, 0);
            }
        }
        __builtin_amdgcn_s_setprio(0);
        __syncthreads();   // single barrier: drains next-tile gll16, syncs buf reuse
        cur = nb;
        kmC0 = kmN0;
        kmC1 = kmN1;
    }

    // ---- epilogue: unnormalized partials (bf16 o, f32 l) ----
    unsigned short* pob = po + (size_t)half * (4096 * 512);
    #pragma unroll
    for (int c = 0; c < 4; c++)
        #pragma unroll
        for (int r = 0; r < 4; r++)
            pob[(size_t)(b * L_LEN + qblk + w * 16 + 4 * g + r) * 512 + hh * 64 + c * 16 + n16]
                = f2bf(o_acc[c][r]);
    if (n16 == 0) {
        #pragma unroll
        for (int r = 0; r < 4; r++)
            pl[(size_t)half * 32768 + (size_t)(b * L_LEN + qblk + w * 16 + 4 * g + r) * 8 + hh]
                = l_acc[r];
    }
}

// ---------------------------------------------------------------------------
// Fused head: out[row] = dot(gelu(xb[row] @ Whb + bh1) * Wh2) + bh2
// One block = 16 rows x 128 cols (wave w -> cols w*32..w*32+31). K=768.
// ---------------------------------------------------------------------------
__global__ __launch_bounds__(256) void head_kernel(
    const unsigned short* __restrict__ A, const unsigned short* __restrict__ Wt,
    const float* __restrict__ bh1, const float* __restrict__ Wh2,
    const float* __restrict__ bh2, float* __restrict__ out)
{
    __shared__ unsigned short sA[2][16][64];
    __shared__ unsigned short sB[2][128][64];
    __shared__ float sRed[4][16];
    const int tid = threadIdx.x;
    const int l = tid & 63, w = tid >> 6;
    const int g = l >> 4, n16 = l & 15;
    const int m0 = blockIdx.x * 16;
    const int r8 = l >> 3;
    const int swz8 = ((l & 7) ^ r8) * 8;

    f32x4 acc[2];
    acc[0] = (f32x4){0.f, 0.f, 0.f, 0.f};
    acc[1] = (f32x4){0.f, 0.f, 0.f, 0.f};

#define HSTAGE(buf, k0)                                                         \
    do {                                                                        \
        if (w < 2) {                                                            \
            int row = w * 8 + r8;                                               \
            gll16(A + (size_t)(m0 + row) * 768 + (k0) + swz8,                   \
                  &sA[buf][w * 8][0]);                                          \
        }                                                                       \
        _Pragma("unroll")                                                       \
        for (int p = 0; p < 4; p++) {                                           \
            int row = w * 32 + p * 8 + r8;                                      \
            gll16(Wt + (size_t)row * 768 + (k0) + swz8,                         \
                  &sB[buf][w * 32 + p * 8][0]);                                 \
        }                                                                       \
    } while (0)

    HSTAGE(0, 0);
    __syncthreads();

    int cur = 0;
    for (int k0 = 0; k0 < 768; k0 += 64) {
        int nxt = cur ^ 1;
        if (k0 + 64 < 768) HSTAGE(nxt, k0 + 64);
        #pragma unroll
        for (int ks = 0; ks < 2; ks++) {
            bf16x8 af = *(const bf16x8*)((const char*)&sA[cur][n16][0]
                         + ((ks * 64 + g * 16) ^ ((n16 & 7) << 4)));
            #pragma unroll
            for (int ni = 0; ni < 2; ni++) {
                int row = w * 32 + ni * 16 + n16;
                bf16x8 bfr = *(const bf16x8*)((const char*)&sB[cur][row][0]
                              + ((ks * 64 + g * 16) ^ ((n16 & 7) << 4)));
                acc[ni] = __builtin_amdgcn_mfma_f32_16x16x32_bf16(af, bfr, acc[ni], 0, 0, 0);
            }
        }
        __syncthreads();
        cur = nxt;
    }
#undef HSTAGE

    float s[4];
    #pragma unroll
    for (int r = 0; r < 4; r++) {
        s[r] = 0.f;
        #pragma unroll
        for (int ni = 0; ni < 2; ni++) {
            int col = w * 32 + ni * 16 + n16;
            s[r] += gelu_f(acc[ni][r] + bh1[col]) * Wh2[col];
        }
        s[r] += __shfl_xor(s[r], 1);
        s[r] += __shfl_xor(s[r], 2);
        s[r] += __shfl_xor(s[r], 4);
        s[r] += __shfl_xor(s[r], 8);
    }
    if (n16 == 0) {
        #pragma unroll
        for (int r = 0; r < 4; r++) sRed[w][4 * g + r] = s[r];
    }
    __syncthreads();
    if (tid < 16)
        out[m0 + tid] = sRed[0][tid] + sRed[1][tid] + sRed[2][tid] + sRed[3][tid] + bh2[0];
}

// ---------------------------------------------------------------------------
extern "C" void kernel_launch(void* const* d_in, const int* in_sizes, int n_in,
                              void* d_out, int out_size, void* d_ws, size_t ws_size,
                              hipStream_t stream)
{
    const float* z      = (const float*)d_in[0];
    const float* cond   = (const float*)d_in[1];
    const float* s      = (const float*)d_in[2];
    const float* Kmat   = (const float*)d_in[3];
    const float* embed  = (const float*)d_in[4];
    const float* W_in1  = (const float*)d_in[5];
    const float* b_in1  = (const float*)d_in[6];
    const float* W_in2  = (const float*)d_in[7];
    const float* b_in2  = (const float*)d_in[8];
    const float* bias_w = (const float*)d_in[9];
    const float* bias_b = (const float*)d_in[10];  // cancels in softmax
    const float* Wq     = (const float*)d_in[11];
    const float* bq     = (const float*)d_in[12];
    const float* Wk     = (const float*)d_in[13];
    const float* bk     = (const float*)d_in[14];
    const float* Wv     = (const float*)d_in[15];
    const float* bv     = (const float*)d_in[16];
    const float* Wo     = (const float*)d_in[17];
    const float* bo     = (const float*)d_in[18];
    const float* ln1_s  = (const float*)d_in[19];
    const float* ln1_b  = (const float*)d_in[20];
    const float* ln2_s  = (const float*)d_in[21];
    const float* ln2_b  = (const float*)d_in[22];
    const float* Wf1    = (const float*)d_in[23];
    const float* bf1    = (const float*)d_in[24];
    const float* Wf2    = (const float*)d_in[25];
    const float* bf2    = (const float*)d_in[26];
    const float* Wh1    = (const float*)d_in[27];
    const float* bh1    = (const float*)d_in[28];
    const float* Wh2    = (const float*)d_in[29];
    const float* bh2    = (const float*)d_in[30];
    float* out = (float*)d_out;
    (void)bias_b;

    const int M = B_SZ * L_LEN; // 4096
    char* base = (char*)d_ws;
    unsigned short* feats = (unsigned short*)base;                     // 4096*576 bf16
    float* x = (float*)(base + (size_t)M * FIN_PAD * 2);               // 4096*256 f32
    unsigned short* h    = (unsigned short*)((char*)x + (size_t)M * D_MOD * 4);
    unsigned short* hid1 = h    + (size_t)M * D_MOD;                   // 4096*1024
    unsigned short* qb   = hid1 + (size_t)M * 1024;                    // 4096*512 (also head xb [4096][768] with kb2)
    unsigned short* kb2  = qb   + (size_t)M * 512;
    unsigned short* vtb  = kb2  + (size_t)M * 512;                     // [2][512][2048]
    unsigned short* ob   = vtb  + (size_t)M * 512;
    unsigned short* wt   = ob   + (size_t)M * 512;                     // WT_END elems
    float* bqkv          = (float*)(wt + WT_END);                      // 2*1536 f32
    unsigned short* kmfrag = (unsigned short*)(bqkv + 2 * 1536);       // [2][1<<22]
    unsigned short* po   = kmfrag + ((size_t)2 << 22);                 // [2][4096][512] bf16
    float* pl            = (float*)(po + (size_t)2 * 4096 * 512);      // [2][4096][8] f32
    (void)ob;

    prep_kernel<<<dim3(3292), dim3(256), 0, stream>>>(
        W_in1, W_in2, Wq, Wk, Wv, Wo, Wf1, Wf2, Wh1, Kmat, bias_w,
        bq, bk, bv, z, s, embed, cond, wt, kmfrag, bqkv, feats);

    gemmW<1, 1><<<dim3(8, 64), 256, 0, stream>>>(feats, wt + OFF_IN1, b_in1, hid1, nullptr, nullptr, M, 1024, FIN_PAD, FIN_PAD);
    gemm_bf16<0, 0, 16, 0><<<dim3(4, 256), 256, 0, stream>>>(hid1, wt + OFF_IN2, b_in2, x, nullptr, nullptr, M, 256, 1024, 1024);

    for (int i = 0; i < NB_BLK; i++) {
        ln_bf16<<<dim3(M / 4), 256, 0, stream>>>(x, ln1_s + i * D_MOD, ln1_b + i * D_MOD, h);
        gemmW<0, 4><<<dim3(12, 64), 256, 0, stream>>>(h, wt + OFF_QKV + (size_t)i * 393216, bqkv + i * 1536, qb, kb2, vtb, M, 1536, 256, 256);
        attn_mfma<<<dim3(1024), 256, 0, stream>>>(qb, kb2, vtb, kmfrag + ((size_t)i << 22), po, pl);
        gemm_bf16<0, 2, 16, 1><<<dim3(4, 256), 256, 0, stream>>>(po, wt + OFF_O + (size_t)i * 131072, bo + i * D_MOD, x, nullptr, pl, M, 256, 512, 512);
        ln_bf16<<<dim3(M / 4), 256, 0, stream>>>(x, ln2_s + i * D_MOD, ln2_b + i * D_MOD, h);
        gemmW<1, 1><<<dim3(8, 64), 256, 0, stream>>>(h, wt + OFF_F1 + (size_t)i * 262144, bf1 + i * 1024, hid1, nullptr, nullptr, M, 1024, 256, 256);
        if (i == 0)
            gemm_bf16<0, 2, 16, 0><<<dim3(4, 256), 256, 0, stream>>>(hid1, wt + OFF_F2 + (size_t)i * 262144, bf2 + i * D_MOD, x, nullptr, nullptr, M, 256, 1024, 1024);
        else
            gemm_bf16<0, 5, 16, 0><<<dim3(4, 256), 256, 0, stream>>>(hid1, wt + OFF_F2 + (size_t)i * 262144, bf2 + i * D_MOD, x, qb, nullptr, M, 256, 1024, 1024);
    }
    head_kernel<<<dim3(256), 256, 0, stream>>>(qb, wt + OFF_H, bh1, Wh2, bh2, out);
}

// Round 19
// 223.227 us; speedup vs baseline: 1.0095x; 1.0092x over previous
//
#include <hip/hip_runtime.h>
#include <math.h>

#define B_SZ 2
#define L_LEN 2048
#define D_MOD 256
#define H_HEADS 8
#define NB_BLK 2
#define S_SZ 2
#define E_SZ 503
#define C_SZ 8
#define FIN 514
#define FIN_PAD 576
#define LOG2E 1.44269504088896340736f
#define QSC (0.125f * LOG2E)

typedef short bf16x8 __attribute__((ext_vector_type(8)));
typedef float f32x4 __attribute__((ext_vector_type(4)));
typedef unsigned short u16x4 __attribute__((ext_vector_type(4)));
typedef unsigned short u16x8 __attribute__((ext_vector_type(8)));

// bf16 weight buffer offsets (elements) inside wt
#define OFF_IN1 0           // [1024][576]
#define OFF_IN2 589824      // [256][1024]
#define OFF_QKV 851968      // [2][1536][256]  rows: 0-511 q(*QSC), 512-1023 k, 1024-1535 v
#define OFF_O   1638400     // [2][256][512]
#define OFF_F1  1900544     // [2][1024][256]
#define OFF_F2  2424832     // [2][256][1024]
#define OFF_H   2949120     // [128][768]  (Whi | Whi | Wlo)
#define WT_END  3047424

__device__ __forceinline__ unsigned short f2bf(float x) {
    unsigned u = __float_as_uint(x);
    u += 0x7FFFu + ((u >> 16) & 1u);
    return (unsigned short)(u >> 16);
}

__device__ __forceinline__ float bf2f(unsigned short h) {
    return __uint_as_float(((unsigned)h) << 16);
}

__device__ __forceinline__ float gelu_f(float x) {
    float x3 = x * x * x;
    return 0.5f * x * (1.0f + tanhf(0.7978845608028654f * (x + 0.044715f * x3)));
}

__device__ __forceinline__ void gll16(const void* g, void* l) {
    __builtin_amdgcn_global_load_lds(
        (const __attribute__((address_space(1))) unsigned int*)g,
        (__attribute__((address_space(3))) unsigned int*)l,
        16, 0, 0);
}

// ---------------------------------------------------------------------------
// Merged prep: [0,720) wprep | [720,1104) hprep | [1104,2128) km_frag (both i)
// | [2128,2140) bprep | [2140,3292) feats (both b, 4 elems/thread)
// km_frag layout: [i][kt*32+qb][lane 0..255][16 bf16]
// value[c*4+r] = LOG2E*bias_w[i]*Kmat[qb*64+16w+4g+r][kt*64+c*16+n16]
// ---------------------------------------------------------------------------
__global__ __launch_bounds__(256) void prep_kernel(
    const float* __restrict__ W_in1, const float* __restrict__ W_in2,
    const float* __restrict__ Wq, const float* __restrict__ Wk,
    const float* __restrict__ Wv, const float* __restrict__ Wo,
    const float* __restrict__ Wf1, const float* __restrict__ Wf2,
    const float* __restrict__ Wh1, const float* __restrict__ Kmat,
    const float* __restrict__ bias_w,
    const float* __restrict__ bq, const float* __restrict__ bk,
    const float* __restrict__ bv,
    const float* __restrict__ z, const float* __restrict__ s,
    const float* __restrict__ embed, const float* __restrict__ cond,
    unsigned short* __restrict__ wt, unsigned short* __restrict__ kmfrag,
    float* __restrict__ bqkv, unsigned short* __restrict__ feats)
{
    __shared__ unsigned short sT[64][65];
    int b = blockIdx.x;
    int t = threadIdx.x;

    if (b < 720) {
        // ---- weight transpose+cast ----
        const float* src; unsigned short* dst; int K, N, Kp, tile;
        float scale = 1.0f;
        if (b < 144)      { src = W_in1; dst = wt + OFF_IN1; K = 514;  N = 1024; Kp = 576;  tile = b; }
        else if (b < 208) { src = W_in2; dst = wt + OFF_IN2; K = 1024; N = 256;  Kp = 1024; tile = b - 144; }
        else if (b < 400) { int t2 = b - 208;
                            int sec = t2 >> 5; tile = t2 & 31;
                            int i = sec / 3, which = sec % 3;
                            const float* wsrc = which == 0 ? Wq : which == 1 ? Wk : Wv;
                            if (which == 0) scale = QSC;
                            src = wsrc + (size_t)i * 131072;
                            dst = wt + OFF_QKV + (size_t)i * 393216 + (size_t)which * 131072;
                            K = 256; N = 512; Kp = 256; }
        else if (b < 464) { int t2 = b - 400; int i = t2 >> 5; tile = t2 & 31;
                            src = Wo + (size_t)i * 131072; dst = wt + OFF_O + (size_t)i * 131072;
                            K = 512; N = 256; Kp = 512; }
        else if (b < 592) { int t2 = b - 464; int i = t2 >> 6; tile = t2 & 63;
                            src = Wf1 + (size_t)i * 262144; dst = wt + OFF_F1 + (size_t)i * 262144;
                            K = 256; N = 1024; Kp = 256; }
        else              { int t2 = b - 592; int i = t2 >> 6; tile = t2 & 63;
                            src = Wf2 + (size_t)i * 262144; dst = wt + OFF_F2 + (size_t)i * 262144;
                            K = 1024; N = 256; Kp = 1024; }

        int nt = N >> 6;
        int kt0 = (tile / nt) << 6;
        int nt0 = (tile % nt) << 6;
        #pragma unroll
        for (int p = 0; p < 4; p++) {
            int r = p * 16 + (t >> 4);
            int c = (t & 15) * 4;
            float4 v4 = make_float4(0.f, 0.f, 0.f, 0.f);
            if (kt0 + r < K) v4 = *(const float4*)(src + (size_t)(kt0 + r) * N + nt0 + c);
            sT[r][c + 0] = f2bf(v4.x * scale);
            sT[r][c + 1] = f2bf(v4.y * scale);
            sT[r][c + 2] = f2bf(v4.z * scale);
            sT[r][c + 3] = f2bf(v4.w * scale);
        }
        __syncthreads();
        int n = t >> 2, kq = (t & 3) * 16;
        u16x8 o0, o1;
        #pragma unroll
        for (int j = 0; j < 8; j++) {
            o0[j] = sT[kq + j][n];
            o1[j] = sT[kq + 8 + j][n];
        }
        unsigned short* dp = dst + (size_t)(nt0 + n) * Kp + kt0 + kq;
        *(u16x8*)(dp) = o0;
        *(u16x8*)(dp + 8) = o1;
    } else if (b < 1104) {
        // ---- head split-precision weights ----
        int idx = (b - 720) * 256 + t;   // 128*768
        if (idx < 128 * 768) {
            int n = idx / 768, kk = idx % 768;
            int kz = kk & 255;
            float v = Wh1[(size_t)kz * 128 + n];
            unsigned short hi = f2bf(v);
            wt[OFF_H + idx] = (kk < 512) ? hi : f2bf(v - bf2f(hi));
        }
    } else if (b < 2128) {
        // ---- km_frag: per-lane attention bias fragments, BOTH layers ----
        int tile = b - 1104;               // [0,1024)
        int kt = tile >> 5, qb = tile & 31;
        float s0 = bias_w[0] * LOG2E, s1 = bias_w[1] * LOG2E;
        int q0 = qb * 64 + ((t >> 6) << 4) + (((t >> 4) & 3) << 2);
        int k0 = kt * 64 + (t & 15);
        u16x8 a0, a1, b0, b1;
        #pragma unroll
        for (int c = 0; c < 4; c++)
            #pragma unroll
            for (int r = 0; r < 4; r++) {
                float v = Kmat[(size_t)(q0 + r) * L_LEN + k0 + c * 16];
                if (c < 2) { a0[c * 4 + r] = f2bf(v * s0); b0[c * 4 + r] = f2bf(v * s1); }
                else       { a1[(c - 2) * 4 + r] = f2bf(v * s0); b1[(c - 2) * 4 + r] = f2bf(v * s1); }
            }
        unsigned short* dp = kmfrag + (((size_t)(kt * 32 + qb)) * 256 + t) * 16;
        *(u16x8*)dp = a0;
        *(u16x8*)(dp + 8) = a1;
        unsigned short* dp1 = dp + ((size_t)1 << 22);
        *(u16x8*)dp1 = b0;
        *(u16x8*)(dp1 + 8) = b1;
    } else if (b < 2140) {
        // ---- fused QKV bias ----
        int idx = (b - 2128) * 256 + t;
        if (idx < 2 * 1536) {
            int i = idx / 1536, c = idx % 1536;
            float v;
            if (c < 512)       v = bq[i * 512 + c] * QSC;
            else if (c < 1024) v = bk[i * 512 + c - 512];
            else               v = bv[i * 512 + c - 1024];
            bqkv[idx] = v;
        }
    } else {
        // ---- feats: 4 elems/thread, both b rows from one read ----
        int idx = (b - 2140) * 256 + t;    // [0, 294912)
        int l = idx / 144;
        int f0 = (idx % 144) * 4;
        u16x4 pk0, pk1;
        #pragma unroll
        for (int j = 0; j < 4; j++) {
            int f = f0 + j;
            float val;
            if (f >= 3 && f < 506)      val = embed[(size_t)l * E_SZ + (f - 3)];
            else if (f >= 1 && f < 3)   val = s[l * S_SZ + (f - 1)];
            else if (f >= 506 && f < FIN) val = cond[f - 506];
            else                        val = 0.0f;
            unsigned short hv = f2bf(val);
            pk0[j] = (f == 0) ? f2bf(z[l]) : hv;
            pk1[j] = (f == 0) ? f2bf(z[L_LEN + l]) : hv;
        }
        *(u16x4*)(feats + (size_t)l * FIN_PAD + f0) = pk0;
        *(u16x4*)(feats + (size_t)(L_LEN + l) * FIN_PAD + f0) = pk1;
    }
}

// ---------------------------------------------------------------------------
// Wide-tile bf16 MFMA GEMM: 64x128 per block, 4 waves each 32x64 (2x4 frags),
// gll16 staging + XOR-swizzled LDS, double-buffered.
// OMODE: 1 = bf16 out, 4 = fused QKV routing
// ---------------------------------------------------------------------------
template<int ACT, int OMODE>
__global__ __launch_bounds__(256) void gemmW(
    const unsigned short* __restrict__ A, const unsigned short* __restrict__ Wt,
    const float* __restrict__ bias, unsigned short* __restrict__ Cb,
    unsigned short* __restrict__ Cbk, unsigned short* __restrict__ Cbv,
    int M, int N, int Kd, int lda)
{
    __shared__ unsigned short sA[2][64][64];
    __shared__ unsigned short sB[2][128][64];
    const int tid = threadIdx.x;
    const int l = tid & 63, w = tid >> 6;
    const int g = l >> 4, n16 = l & 15;
    const int wr = w >> 1, wc = w & 1;
    const int m0 = blockIdx.y * 64, n0 = blockIdx.x * 128;
    const int r8 = l >> 3;
    const int swz8 = ((l & 7) ^ r8) * 8;

    f32x4 acc[2][4];
    #pragma unroll
    for (int mi = 0; mi < 2; mi++)
        #pragma unroll
        for (int ni = 0; ni < 4; ni++)
            acc[mi][ni] = (f32x4){0.f, 0.f, 0.f, 0.f};

#define STAGEW(buf, k0)                                                         \
    do {                                                                        \
        _Pragma("unroll")                                                       \
        for (int p = 0; p < 2; p++) {                                           \
            int row = w * 16 + p * 8 + r8;                                      \
            gll16(A + (size_t)(m0 + row) * lda + (k0) + swz8,                   \
                  &sA[buf][w * 16 + p * 8][0]);                                 \
        }                                                                       \
        _Pragma("unroll")                                                       \
        for (int p = 0; p < 4; p++) {                                           \
            int row = w * 32 + p * 8 + r8;                                      \
            gll16(Wt + (size_t)(n0 + row) * Kd + (k0) + swz8,                   \
                  &sB[buf][w * 32 + p * 8][0]);                                 \
        }                                                                       \
    } while (0)

    STAGEW(0, 0);
    __syncthreads();

    int cur = 0;
    for (int k0 = 0; k0 < Kd; k0 += 64) {
        int nxt = cur ^ 1;
        if (k0 + 64 < Kd) STAGEW(nxt, k0 + 64);
        #pragma unroll
        for (int ks = 0; ks < 2; ks++) {
            bf16x8 af[2], bfr[4];
            #pragma unroll
            for (int mi = 0; mi < 2; mi++) {
                int row = wr * 32 + mi * 16 + n16;
                af[mi] = *(const bf16x8*)((const char*)&sA[cur][row][0]
                          + ((ks * 64 + g * 16) ^ ((n16 & 7) << 4)));
            }
            #pragma unroll
            for (int ni = 0; ni < 4; ni++) {
                int row = wc * 64 + ni * 16 + n16;
                bfr[ni] = *(const bf16x8*)((const char*)&sB[cur][row][0]
                          + ((ks * 64 + g * 16) ^ ((n16 & 7) << 4)));
            }
            #pragma unroll
            for (int mi = 0; mi < 2; mi++)
                #pragma unroll
                for (int ni = 0; ni < 4; ni++)
                    acc[mi][ni] = __builtin_amdgcn_mfma_f32_16x16x32_bf16(
                        af[mi], bfr[ni], acc[mi][ni], 0, 0, 0);
        }
        __syncthreads();
        cur = nxt;
    }
#undef STAGEW

    #pragma unroll
    for (int mi = 0; mi < 2; mi++) {
        #pragma unroll
        for (int ni = 0; ni < 4; ni++) {
            int col = n0 + wc * 64 + ni * 16 + n16;
            float bv = bias[col];
            #pragma unroll
            for (int r = 0; r < 4; r++) {
                int row = m0 + wr * 32 + mi * 16 + 4 * g + r;
                float val = acc[mi][ni][r] + bv;
                if (ACT == 1) val = gelu_f(val);
                if (OMODE == 1) {
                    Cb[(size_t)row * N + col] = f2bf(val);
                } else {
                    if (col < 1024) {
                        unsigned short* dst = (col < 512) ? Cb : Cbk;
                        dst[(size_t)row * 512 + (col & 511)] = f2bf(val);
                    } else {
                        Cbv[((size_t)(row >> 11) * 512 + (col - 1024)) * L_LEN + (row & (L_LEN - 1))] = f2bf(val);
                    }
                }
            }
        }
    }
}

// ---------------------------------------------------------------------------
// 64-wide bf16 MFMA GEMM (double-buffered). BM = 64, 32, or 16.
// OMODE: 0 = f32 out, 1 = bf16 out, 2 = f32 +=, 5 = f32-residual + split-bf16
// ---------------------------------------------------------------------------
template<int ACT, int OMODE, int BM>
__global__ __launch_bounds__(256) void gemm_bf16(
    const unsigned short* __restrict__ A, const unsigned short* __restrict__ Wt,
    const float* __restrict__ bias, float* __restrict__ Cf,
    unsigned short* __restrict__ Cb, int M, int N, int Kd, int lda)
{
    __shared__ unsigned short sA[2][BM][64];
    __shared__ unsigned short sB[2][64][64];
    const int tid = threadIdx.x;
    const int l = tid & 63, w = tid >> 6;
    const int g = l >> 4, n16 = l & 15;
    const int m0 = blockIdx.y * BM, n0 = blockIdx.x * 64;

    const int r8 = l >> 3;
    const int swz8 = ((l & 7) ^ r8) * 8;

    const int NMI = (BM == 64) ? 2 : 1;
    const int NNI = (BM == 16) ? 1 : 2;
    const int wr = w >> 1;
    const int wc = w & 1;

    f32x4 acc[2][2];
    #pragma unroll
    for (int mi = 0; mi < 2; mi++)
        #pragma unroll
        for (int ni = 0; ni < 2; ni++)
            acc[mi][ni] = (f32x4){0.f, 0.f, 0.f, 0.f};

#define STAGE(buf, k0)                                                          \
    do {                                                                        \
        if (BM == 64) {                                                         \
            _Pragma("unroll")                                                   \
            for (int p = 0; p < 2; p++) {                                       \
                int row = w * 16 + p * 8 + r8;                                  \
                gll16(A + (size_t)(m0 + row) * lda + (k0) + swz8,               \
                      &sA[buf][w * 16 + p * 8][0]);                             \
            }                                                                   \
        } else if (BM == 32) {                                                  \
            int row = w * 8 + r8;                                               \
            gll16(A + (size_t)(m0 + row) * lda + (k0) + swz8,                   \
                  &sA[buf][w * 8][0]);                                          \
        } else {                                                                \
            if (w < 2) {                                                        \
                int row = w * 8 + r8;                                           \
                gll16(A + (size_t)(m0 + row) * lda + (k0) + swz8,               \
                      &sA[buf][w * 8][0]);                                      \
            }                                                                   \
        }                                                                       \
        _Pragma("unroll")                                                       \
        for (int p = 0; p < 2; p++) {                                           \
            int row = w * 16 + p * 8 + r8;                                      \
            gll16(Wt + (size_t)(n0 + row) * Kd + (k0) + swz8,                   \
                  &sB[buf][w * 16 + p * 8][0]);                                 \
        }                                                                       \
    } while (0)

    STAGE(0, 0);
    __syncthreads();

    int cur = 0;
    for (int k0 = 0; k0 < Kd; k0 += 64) {
        int nxt = cur ^ 1;
        if (k0 + 64 < Kd) STAGE(nxt, k0 + 64);
        #pragma unroll
        for (int ks = 0; ks < 2; ks++) {
            bf16x8 af[2], bfr[2];
            #pragma unroll
            for (int mi = 0; mi < NMI; mi++) {
                int row = (BM == 64) ? (wr * 32 + mi * 16 + n16)
                        : (BM == 32) ? (wr * 16 + n16) : n16;
                af[mi] = *(const bf16x8*)((const char*)&sA[cur][row][0]
                          + ((ks * 64 + g * 16) ^ ((n16 & 7) << 4)));
            }
            #pragma unroll
            for (int ni = 0; ni < NNI; ni++) {
                int row = (BM == 16) ? (w * 16 + n16) : (wc * 32 + ni * 16 + n16);
                bfr[ni] = *(const bf16x8*)((const char*)&sB[cur][row][0]
                          + ((ks * 64 + g * 16) ^ ((n16 & 7) << 4)));
            }
            #pragma unroll
            for (int mi = 0; mi < NMI; mi++)
                #pragma unroll
                for (int ni = 0; ni < NNI; ni++)
                    acc[mi][ni] = __builtin_amdgcn_mfma_f32_16x16x32_bf16(
                        af[mi], bfr[ni], acc[mi][ni], 0, 0, 0);
        }
        __syncthreads();
        cur = nxt;
    }
#undef STAGE

    #pragma unroll
    for (int mi = 0; mi < NMI; mi++) {
        #pragma unroll
        for (int ni = 0; ni < NNI; ni++) {
            int col = (BM == 16) ? (n0 + w * 16 + n16)
                                 : (n0 + wc * 32 + ni * 16 + n16);
            float bv = bias[col];
            #pragma unroll
            for (int r = 0; r < 4; r++) {
                int row = (BM == 64) ? (m0 + wr * 32 + mi * 16 + 4 * g + r)
                        : (BM == 32) ? (m0 + wr * 16 + 4 * g + r)
                                     : (m0 + 4 * g + r);
                float val = acc[mi][ni][r] + bv;
                if (ACT == 1) val = gelu_f(val);
                if (OMODE == 0) {
                    Cf[(size_t)row * N + col] = val;
                } else if (OMODE == 1) {
                    Cb[(size_t)row * N + col] = f2bf(val);
                } else if (OMODE == 2) {
                    float* cp = Cf + (size_t)row * N + col;
                    *cp += val;
                } else if (OMODE == 5) {
                    float xnew = Cf[(size_t)row * N + col] + val;
                    unsigned short hi = f2bf(xnew);
                    unsigned short lo = f2bf(xnew - bf2f(hi));
                    unsigned short* orow = Cb + (size_t)row * 768;
                    orow[col] = hi;
                    orow[256 + col] = lo;
                    orow[512 + col] = hi;
                }
            }
        }
    }
}

// ---------------------------------------------------------------------------
// LayerNorm: x f32 -> h bf16
// ---------------------------------------------------------------------------
__global__ __launch_bounds__(256) void ln_bf16(
    const float* __restrict__ x, const float* __restrict__ sc,
    const float* __restrict__ bi, unsigned short* __restrict__ out)
{
    int wave = threadIdx.x >> 6, lane = threadIdx.x & 63;
    int row = blockIdx.x * 4 + wave;
    const float* xr = x + (size_t)row * D_MOD;
    float4 v = *(const float4*)(xr + lane * 4);
    float s1 = v.x + v.y + v.z + v.w;
    float s2 = v.x * v.x + v.y * v.y + v.z * v.z + v.w * v.w;
    #pragma unroll
    for (int off = 1; off < 64; off <<= 1) {
        s1 += __shfl_xor(s1, off);
        s2 += __shfl_xor(s2, off);
    }
    float mean = s1 * (1.0f / 256.0f);
    float var = s2 * (1.0f / 256.0f) - mean * mean;
    float rs = rsqrtf(var + 1e-6f);
    float4 scv = *(const float4*)(sc + lane * 4);
    float4 bv  = *(const float4*)(bi + lane * 4);
    u16x4 o4;
    o4[0] = f2bf((v.x - mean) * rs * scv.x + bv.x);
    o4[1] = f2bf((v.y - mean) * rs * scv.y + bv.y);
    o4[2] = f2bf((v.z - mean) * rs * scv.z + bv.z);
    o4[3] = f2bf((v.w - mean) * rs * scv.w + bv.w);
    *(u16x4*)(out + (size_t)row * D_MOD + lane * 4) = o4;
}

// ---------------------------------------------------------------------------
// MFMA flash attention, split-K x2: grid 1024 = 4 blocks/CU. Each block does
// 16 k-tiles (half the key range) for 64 q rows of one (b,hh). Fixed-max
// softmax -> partials combine exactly. km bias via per-lane register
// fragments (coalesced). One barrier per tile. sP XOR-swizzled (no pad) so
// LDS = 40960 B -> 4 blocks/CU. Writes unnormalized bf16 o + f32 l.
// ---------------------------------------------------------------------------
__global__ __launch_bounds__(256, 4) void attn_mfma(
    const unsigned short* __restrict__ q, const unsigned short* __restrict__ k,
    const unsigned short* __restrict__ vt, const unsigned short* __restrict__ kmf,
    unsigned short* __restrict__ po, float* __restrict__ pl)
{
    __shared__ unsigned short sK[2][64][64];
    __shared__ unsigned short sV[2][64][64];    // V^T tile [d][key]
    __shared__ unsigned short sP[4][16][64];    // XOR-swizzled, no pad

    const int tid = threadIdx.x;
    const int l = tid & 63, w = tid >> 6;
    const int g = l >> 4, n16 = l & 15;

    // XCD-aware decomposition of the 1D 1024-block grid
    const int id = blockIdx.x;
    const int xcd = id & 7, rest = id >> 3;     // rest 0..127
    const int panel = xcd * 2 + (rest & 1);
    const int sub = rest >> 1;                  // 0..63
    const int half = sub & 1;
    const int qi = sub >> 1;                    // 0..31
    const int qblk = qi * 64, hh = panel & 7, b = panel >> 3;
    const int kv0 = half * 1024;

    const int r8 = l >> 3;
    const int swz8 = ((l & 7) ^ r8) * 8;

    bf16x8 qf[2];
    {
        const unsigned short* qp = q + (size_t)(b * L_LEN + qblk + w * 16 + n16) * 512 + hh * 64;
        qf[0] = *(const bf16x8*)(qp + g * 8);
        qf[1] = *(const bf16x8*)(qp + 32 + g * 8);
    }
    bf16x8 onesf;
    #pragma unroll
    for (int j = 0; j < 8; j++) onesf[j] = (short)0x3F80;

    f32x4 o_acc[4];
    #pragma unroll
    for (int c = 0; c < 4; c++) o_acc[c] = (f32x4){0.f, 0.f, 0.f, 0.f};
    f32x4 l_acc = (f32x4){0.f, 0.f, 0.f, 0.f};

    const unsigned short* kbase = k + ((size_t)(b * L_LEN) + kv0) * 512 + hh * 64;
    const unsigned short* vbase = vt + ((size_t)b * 512 + hh * 64) * L_LEN + kv0;
    const unsigned short* kmbase = kmf + (((size_t)qi * 256 + tid) * 16)
                                 + (size_t)(half * 16) * 131072;

    // ---- prologue: tile 0 ----
    #pragma unroll
    for (int p = 0; p < 2; p++) {
        int row = w * 16 + p * 8 + r8;
        gll16(kbase + (size_t)row * 512 + swz8, &sK[0][w * 16 + p * 8][0]);
        gll16(vbase + (size_t)row * L_LEN + swz8, &sV[0][w * 16 + p * 8][0]);
    }
    u16x8 kmC0 = *(const u16x8*)kmbase;
    u16x8 kmC1 = *(const u16x8*)(kmbase + 8);
    __syncthreads();

    int cur = 0;
    for (int kt = 0; kt < 16; kt++) {
        const int nb = cur ^ 1;
        const int kblk2 = (kt + 1) << 6;
        u16x8 kmN0 = kmC0, kmN1 = kmC1;
        if (kt + 1 < 16) {
            #pragma unroll
            for (int p = 0; p < 2; p++) {
                int row = w * 16 + p * 8 + r8;
                gll16(kbase + (size_t)(kblk2 + row) * 512 + swz8, &sK[nb][w * 16 + p * 8][0]);
                gll16(vbase + (size_t)row * L_LEN + kblk2 + swz8, &sV[nb][w * 16 + p * 8][0]);
            }
            const unsigned short* kp2 = kmbase + (size_t)(kt + 1) * 131072;
            kmN0 = *(const u16x8*)kp2;
            kmN1 = *(const u16x8*)(kp2 + 8);
        }
        // ---- km fragment -> MFMA C-init ----
        f32x4 sacc[4];
        #pragma unroll
        for (int c = 0; c < 4; c++)
            #pragma unroll
            for (int r = 0; r < 4; r++)
                sacc[c][r] = bf2f((unsigned short)(c < 2 ? kmC0[c * 4 + r] : kmC1[(c - 2) * 4 + r]));
        // ---- QK^T (accumulates onto km) ----
        __builtin_amdgcn_s_setprio(1);
        #pragma unroll
        for (int ks = 0; ks < 2; ks++)
            #pragma unroll
            for (int c = 0; c < 4; c++) {
                int row = c * 16 + n16;
                bf16x8 kf = *(const bf16x8*)((const char*)&sK[cur][row][0]
                             + ((ks * 64 + g * 16) ^ ((n16 & 7) << 4)));
                sacc[c] = __builtin_amdgcn_mfma_f32_16x16x32_bf16(qf[ks], kf, sacc[c], 0, 0, 0);
            }
        __builtin_amdgcn_s_setprio(0);
        // ---- p = exp2(score) ----
        float p[4][4];
        #pragma unroll
        for (int r = 0; r < 4; r++)
            #pragma unroll
            for (int c = 0; c < 4; c++)
                p[r][c] = __builtin_amdgcn_exp2f(sacc[c][r]);
        // ---- P -> per-wave LDS (bf16), XOR-swizzled cols ----
        #pragma unroll
        for (int r = 0; r < 4; r++) {
            int prow = 4 * g + r;
            #pragma unroll
            for (int c = 0; c < 4; c++)
                sP[w][prow][(c * 16 + n16) ^ ((prow & 7) << 3)] = f2bf(p[r][c]);
        }
        // ---- PV + l-sum ----
        __builtin_amdgcn_s_setprio(1);
        #pragma unroll
        for (int ks = 0; ks < 2; ks++) {
            bf16x8 pf = *(const bf16x8*)((const char*)&sP[w][n16][0]
                         + (((ks * 32 + g * 8) ^ ((n16 & 7) << 3)) * 2));
            l_acc = __builtin_amdgcn_mfma_f32_16x16x32_bf16(pf, onesf, l_acc, 0, 0, 0);
            #pragma unroll
            for (int c = 0; c < 4; c++) {
                int row = c * 16 + n16;
                bf16x8 vf = *(const bf16x8*)((const char*)&sV[cur][row][0]
                             + ((ks * 64 + g * 16) ^ ((n16 & 7) << 4)));
                o_acc[c] = __builtin_amdgcn_mfma_f32_16x16x32_bf16(pf, vf, o_acc[c], 0, 0, 0);
            }
        }
        __builtin_amdgcn_s_setprio(0);
        __syncthreads();   // single barrier: drains next-tile gll16, syncs buf reuse
        cur = nb;
        kmC0 = kmN0;
        kmC1 = kmN1;
    }

    // ---- epilogue: unnormalized partials (bf16 o, f32 l) ----
    unsigned short* pob = po + (size_t)half * (4096 * 512);
    #pragma unroll
    for (int c = 0; c < 4; c++)
        #pragma unroll
        for (int r = 0; r < 4; r++)
            pob[(size_t)(b * L_LEN + qblk + w * 16 + 4 * g + r) * 512 + hh * 64 + c * 16 + n16]
                = f2bf(o_acc[c][r]);
    if (n16 == 0) {
        #pragma unroll
        for (int r = 0; r < 4; r++)
            pl[(size_t)half * 32768 + (size_t)(b * L_LEN + qblk + w * 16 + 4 * g + r) * 8 + hh]
                = l_acc[r];
    }
}

// ---------------------------------------------------------------------------
// Combine split-K partials: ob = (po0+po1)/(l0+l1), bf16. 8 elems/thread.
// ---------------------------------------------------------------------------
__global__ __launch_bounds__(256) void attn_combine(
    const unsigned short* __restrict__ po, const float* __restrict__ pl,
    unsigned short* __restrict__ ob)
{
    int idx = (blockIdx.x * 256 + threadIdx.x) * 8;   // into 4096*512
    int row = idx >> 9, hh = (idx & 511) >> 6;
    u16x8 a = *(const u16x8*)(po + idx);
    u16x8 b8 = *(const u16x8*)(po + (size_t)(4096 * 512) + idx);
    float l0 = pl[(size_t)row * 8 + hh];
    float l1 = pl[32768 + (size_t)row * 8 + hh];
    float inv = 1.0f / (l0 + l1);
    u16x8 o;
    #pragma unroll
    for (int j = 0; j < 8; j++)
        o[j] = f2bf((bf2f((unsigned short)a[j]) + bf2f((unsigned short)b8[j])) * inv);
    *(u16x8*)(ob + idx) = o;
}

// ---------------------------------------------------------------------------
// Fused head: out[row] = dot(gelu(xb[row] @ Whb + bh1) * Wh2) + bh2
// One block = 16 rows x 128 cols (wave w -> cols w*32..w*32+31). K=768.
// ---------------------------------------------------------------------------
__global__ __launch_bounds__(256) void head_kernel(
    const unsigned short* __restrict__ A, const unsigned short* __restrict__ Wt,
    const float* __restrict__ bh1, const float* __restrict__ Wh2,
    const float* __restrict__ bh2, float* __restrict__ out)
{
    __shared__ unsigned short sA[2][16][64];
    __shared__ unsigned short sB[2][128][64];
    __shared__ float sRed[4][16];
    const int tid = threadIdx.x;
    const int l = tid & 63, w = tid >> 6;
    const int g = l >> 4, n16 = l & 15;
    const int m0 = blockIdx.x * 16;
    const int r8 = l >> 3;
    const int swz8 = ((l & 7) ^ r8) * 8;

    f32x4 acc[2];
    acc[0] = (f32x4){0.f, 0.f, 0.f, 0.f};
    acc[1] = (f32x4){0.f, 0.f, 0.f, 0.f};

#define HSTAGE(buf, k0)                                                         \
    do {                                                                        \
        if (w < 2) {                                                            \
            int row = w * 8 + r8;                                               \
            gll16(A + (size_t)(m0 + row) * 768 + (k0) + swz8,                   \
                  &sA[buf][w * 8][0]);                                          \
        }                                                                       \
        _Pragma("unroll")                                                       \
        for (int p = 0; p < 4; p++) {                                           \
            int row = w * 32 + p * 8 + r8;                                      \
            gll16(Wt + (size_t)row * 768 + (k0) + swz8,                         \
                  &sB[buf][w * 32 + p * 8][0]);                                 \
        }                                                                       \
    } while (0)

    HSTAGE(0, 0);
    __syncthreads();

    int cur = 0;
    for (int k0 = 0; k0 < 768; k0 += 64) {
        int nxt = cur ^ 1;
        if (k0 + 64 < 768) HSTAGE(nxt, k0 + 64);
        #pragma unroll
        for (int ks = 0; ks < 2; ks++) {
            bf16x8 af = *(const bf16x8*)((const char*)&sA[cur][n16][0]
                         + ((ks * 64 + g * 16) ^ ((n16 & 7) << 4)));
            #pragma unroll
            for (int ni = 0; ni < 2; ni++) {
                int row = w * 32 + ni * 16 + n16;
                bf16x8 bfr = *(const bf16x8*)((const char*)&sB[cur][row][0]
                              + ((ks * 64 + g * 16) ^ ((n16 & 7) << 4)));
                acc[ni] = __builtin_amdgcn_mfma_f32_16x16x32_bf16(af, bfr, acc[ni], 0, 0, 0);
            }
        }
        __syncthreads();
        cur = nxt;
    }
#undef HSTAGE

    float s[4];
    #pragma unroll
    for (int r = 0; r < 4; r++) {
        s[r] = 0.f;
        #pragma unroll
        for (int ni = 0; ni < 2; ni++) {
            int col = w * 32 + ni * 16 + n16;
            s[r] += gelu_f(acc[ni][r] + bh1[col]) * Wh2[col];
        }
        s[r] += __shfl_xor(s[r], 1);
        s[r] += __shfl_xor(s[r], 2);
        s[r] += __shfl_xor(s[r], 4);
        s[r] += __shfl_xor(s[r], 8);
    }
    if (n16 == 0) {
        #pragma unroll
        for (int r = 0; r < 4; r++) sRed[w][4 * g + r] = s[r];
    }
    __syncthreads();
    if (tid < 16)
        out[m0 + tid] = sRed[0][tid] + sRed[1][tid] + sRed[2][tid] + sRed[3][tid] + bh2[0];
}

// ---------------------------------------------------------------------------
extern "C" void kernel_launch(void* const* d_in, const int* in_sizes, int n_in,
                              void* d_out, int out_size, void* d_ws, size_t ws_size,
                              hipStream_t stream)
{
    const float* z      = (const float*)d_in[0];
    const float* cond   = (const float*)d_in[1];
    const float* s      = (const float*)d_in[2];
    const float* Kmat   = (const float*)d_in[3];
    const float* embed  = (const float*)d_in[4];
    const float* W_in1  = (const float*)d_in[5];
    const float* b_in1  = (const float*)d_in[6];
    const float* W_in2  = (const float*)d_in[7];
    const float* b_in2  = (const float*)d_in[8];
    const float* bias_w = (const float*)d_in[9];
    const float* bias_b = (const float*)d_in[10];  // cancels in softmax
    const float* Wq     = (const float*)d_in[11];
    const float* bq     = (const float*)d_in[12];
    const float* Wk     = (const float*)d_in[13];
    const float* bk     = (const float*)d_in[14];
    const float* Wv     = (const float*)d_in[15];
    const float* bv     = (const float*)d_in[16];
    const float* Wo     = (const float*)d_in[17];
    const float* bo     = (const float*)d_in[18];
    const float* ln1_s  = (const float*)d_in[19];
    const float* ln1_b  = (const float*)d_in[20];
    const float* ln2_s  = (const float*)d_in[21];
    const float* ln2_b  = (const float*)d_in[22];
    const float* Wf1    = (const float*)d_in[23];
    const float* bf1    = (const float*)d_in[24];
    const float* Wf2    = (const float*)d_in[25];
    const float* bf2    = (const float*)d_in[26];
    const float* Wh1    = (const float*)d_in[27];
    const float* bh1    = (const float*)d_in[28];
    const float* Wh2    = (const float*)d_in[29];
    const float* bh2    = (const float*)d_in[30];
    float* out = (float*)d_out;
    (void)bias_b;

    const int M = B_SZ * L_LEN; // 4096
    char* base = (char*)d_ws;
    unsigned short* feats = (unsigned short*)base;                     // 4096*576 bf16
    float* x = (float*)(base + (size_t)M * FIN_PAD * 2);               // 4096*256 f32
    unsigned short* h    = (unsigned short*)((char*)x + (size_t)M * D_MOD * 4);
    unsigned short* hid1 = h    + (size_t)M * D_MOD;                   // 4096*1024
    unsigned short* qb   = hid1 + (size_t)M * 1024;                    // 4096*512 (also head xb [4096][768] with kb2)
    unsigned short* kb2  = qb   + (size_t)M * 512;
    unsigned short* vtb  = kb2  + (size_t)M * 512;                     // [2][512][2048]
    unsigned short* ob   = vtb  + (size_t)M * 512;
    unsigned short* wt   = ob   + (size_t)M * 512;                     // WT_END elems
    float* bqkv          = (float*)(wt + WT_END);                      // 2*1536 f32
    unsigned short* kmfrag = (unsigned short*)(bqkv + 2 * 1536);       // [2][1<<22]
    unsigned short* po   = kmfrag + ((size_t)2 << 22);                 // [2][4096][512] bf16
    float* pl            = (float*)(po + (size_t)2 * 4096 * 512);      // [2][4096][8] f32

    prep_kernel<<<dim3(3292), dim3(256), 0, stream>>>(
        W_in1, W_in2, Wq, Wk, Wv, Wo, Wf1, Wf2, Wh1, Kmat, bias_w,
        bq, bk, bv, z, s, embed, cond, wt, kmfrag, bqkv, feats);

    gemmW<1, 1><<<dim3(8, 64), 256, 0, stream>>>(feats, wt + OFF_IN1, b_in1, hid1, nullptr, nullptr, M, 1024, FIN_PAD, FIN_PAD);
    gemm_bf16<0, 0, 16><<<dim3(4, 256), 256, 0, stream>>>(hid1, wt + OFF_IN2, b_in2, x, nullptr, M, 256, 1024, 1024);

    for (int i = 0; i < NB_BLK; i++) {
        ln_bf16<<<dim3(M / 4), 256, 0, stream>>>(x, ln1_s + i * D_MOD, ln1_b + i * D_MOD, h);
        gemmW<0, 4><<<dim3(12, 64), 256, 0, stream>>>(h, wt + OFF_QKV + (size_t)i * 393216, bqkv + i * 1536, qb, kb2, vtb, M, 1536, 256, 256);
        attn_mfma<<<dim3(1024), 256, 0, stream>>>(qb, kb2, vtb, kmfrag + ((size_t)i << 22), po, pl);
        attn_combine<<<dim3(1024), 256, 0, stream>>>(po, pl, ob);
        gemm_bf16<0, 2, 16><<<dim3(4, 256), 256, 0, stream>>>(ob, wt + OFF_O + (size_t)i * 131072, bo + i * D_MOD, x, nullptr, M, 256, 512, 512);
        ln_bf16<<<dim3(M / 4), 256, 0, stream>>>(x, ln2_s + i * D_MOD, ln2_b + i * D_MOD, h);
        gemmW<1, 1><<<dim3(8, 64), 256, 0, stream>>>(h, wt + OFF_F1 + (size_t)i * 262144, bf1 + i * 1024, hid1, nullptr, nullptr, M, 1024, 256, 256);
        if (i == 0)
            gemm_bf16<0, 2, 16><<<dim3(4, 256), 256, 0, stream>>>(hid1, wt + OFF_F2 + (size_t)i * 262144, bf2 + i * D_MOD, x, nullptr, M, 256, 1024, 1024);
        else
            gemm_bf16<0, 5, 16><<<dim3(4, 256), 256, 0, stream>>>(hid1, wt + OFF_F2 + (size_t)i * 262144, bf2 + i * D_MOD, x, qb, M, 256, 1024, 1024);
    }
    head_kernel<<<dim3(256), 256, 0, stream>>>(qb, wt + OFF_H, bh1, Wh2, bh2, out);
}

// Round 20
// 222.599 us; speedup vs baseline: 1.0124x; 1.0028x over previous
//
#include <hip/hip_runtime.h>
#include <math.h>

#define B_SZ 2
#define L_LEN 2048
#define D_MOD 256
#define H_HEADS 8
#define NB_BLK 2
#define S_SZ 2
#define E_SZ 503
#define C_SZ 8
#define FIN 514
#define FIN_PAD 576
#define LOG2E 1.44269504088896340736f
#define QSC (0.125f * LOG2E)

typedef short bf16x8 __attribute__((ext_vector_type(8)));
typedef float f32x4 __attribute__((ext_vector_type(4)));
typedef unsigned short u16x4 __attribute__((ext_vector_type(4)));
typedef unsigned short u16x8 __attribute__((ext_vector_type(8)));

// bf16 weight buffer offsets (elements) inside wt
#define OFF_IN1 0           // [1024][576]
#define OFF_IN2 589824      // [256][1024]
#define OFF_QKV 851968      // [2][1536][256]  rows: 0-511 q(*QSC), 512-1023 k, 1024-1535 v
#define OFF_O   1638400     // [2][256][512]
#define OFF_F1  1900544     // [2][1024][256]
#define OFF_F2  2424832     // [2][256][1024]
#define OFF_H   2949120     // [128][768]  (Whi | Whi | Wlo)
#define WT_END  3047424

__device__ __forceinline__ unsigned short f2bf(float x) {
    unsigned u = __float_as_uint(x);
    u += 0x7FFFu + ((u >> 16) & 1u);
    return (unsigned short)(u >> 16);
}

__device__ __forceinline__ float bf2f(unsigned short h) {
    return __uint_as_float(((unsigned)h) << 16);
}

__device__ __forceinline__ float gelu_f(float x) {
    float x3 = x * x * x;
    return 0.5f * x * (1.0f + tanhf(0.7978845608028654f * (x + 0.044715f * x3)));
}

__device__ __forceinline__ void gll16(const void* g, void* l) {
    __builtin_amdgcn_global_load_lds(
        (const __attribute__((address_space(1))) unsigned int*)g,
        (__attribute__((address_space(3))) unsigned int*)l,
        16, 0, 0);
}

// ---------------------------------------------------------------------------
// Merged prep: [0,720) wprep | [720,1104) hprep | [1104,2128) km_frag (both i)
// | [2128,2140) bprep | [2140,3292) feats (both b, 4 elems/thread)
// km_frag layout: [i][kt*32+qb][lane 0..255][16 bf16]
// value[c*4+r] = LOG2E*bias_w[i]*Kmat[qb*64+16w+4g+r][kt*64+c*16+n16]
// ---------------------------------------------------------------------------
__global__ __launch_bounds__(256) void prep_kernel(
    const float* __restrict__ W_in1, const float* __restrict__ W_in2,
    const float* __restrict__ Wq, const float* __restrict__ Wk,
    const float* __restrict__ Wv, const float* __restrict__ Wo,
    const float* __restrict__ Wf1, const float* __restrict__ Wf2,
    const float* __restrict__ Wh1, const float* __restrict__ Kmat,
    const float* __restrict__ bias_w,
    const float* __restrict__ bq, const float* __restrict__ bk,
    const float* __restrict__ bv,
    const float* __restrict__ z, const float* __restrict__ s,
    const float* __restrict__ embed, const float* __restrict__ cond,
    unsigned short* __restrict__ wt, unsigned short* __restrict__ kmfrag,
    float* __restrict__ bqkv, unsigned short* __restrict__ feats)
{
    __shared__ unsigned short sT[64][65];
    int b = blockIdx.x;
    int t = threadIdx.x;

    if (b < 720) {
        // ---- weight transpose+cast ----
        const float* src; unsigned short* dst; int K, N, Kp, tile;
        float scale = 1.0f;
        if (b < 144)      { src = W_in1; dst = wt + OFF_IN1; K = 514;  N = 1024; Kp = 576;  tile = b; }
        else if (b < 208) { src = W_in2; dst = wt + OFF_IN2; K = 1024; N = 256;  Kp = 1024; tile = b - 144; }
        else if (b < 400) { int t2 = b - 208;
                            int sec = t2 >> 5; tile = t2 & 31;
                            int i = sec / 3, which = sec % 3;
                            const float* wsrc = which == 0 ? Wq : which == 1 ? Wk : Wv;
                            if (which == 0) scale = QSC;
                            src = wsrc + (size_t)i * 131072;
                            dst = wt + OFF_QKV + (size_t)i * 393216 + (size_t)which * 131072;
                            K = 256; N = 512; Kp = 256; }
        else if (b < 464) { int t2 = b - 400; int i = t2 >> 5; tile = t2 & 31;
                            src = Wo + (size_t)i * 131072; dst = wt + OFF_O + (size_t)i * 131072;
                            K = 512; N = 256; Kp = 512; }
        else if (b < 592) { int t2 = b - 464; int i = t2 >> 6; tile = t2 & 63;
                            src = Wf1 + (size_t)i * 262144; dst = wt + OFF_F1 + (size_t)i * 262144;
                            K = 256; N = 1024; Kp = 256; }
        else              { int t2 = b - 592; int i = t2 >> 6; tile = t2 & 63;
                            src = Wf2 + (size_t)i * 262144; dst = wt + OFF_F2 + (size_t)i * 262144;
                            K = 1024; N = 256; Kp = 1024; }

        int nt = N >> 6;
        int kt0 = (tile / nt) << 6;
        int nt0 = (tile % nt) << 6;
        #pragma unroll
        for (int p = 0; p < 4; p++) {
            int r = p * 16 + (t >> 4);
            int c = (t & 15) * 4;
            float4 v4 = make_float4(0.f, 0.f, 0.f, 0.f);
            if (kt0 + r < K) v4 = *(const float4*)(src + (size_t)(kt0 + r) * N + nt0 + c);
            sT[r][c + 0] = f2bf(v4.x * scale);
            sT[r][c + 1] = f2bf(v4.y * scale);
            sT[r][c + 2] = f2bf(v4.z * scale);
            sT[r][c + 3] = f2bf(v4.w * scale);
        }
        __syncthreads();
        int n = t >> 2, kq = (t & 3) * 16;
        u16x8 o0, o1;
        #pragma unroll
        for (int j = 0; j < 8; j++) {
            o0[j] = sT[kq + j][n];
            o1[j] = sT[kq + 8 + j][n];
        }
        unsigned short* dp = dst + (size_t)(nt0 + n) * Kp + kt0 + kq;
        *(u16x8*)(dp) = o0;
        *(u16x8*)(dp + 8) = o1;
    } else if (b < 1104) {
        // ---- head split-precision weights ----
        int idx = (b - 720) * 256 + t;   // 128*768
        if (idx < 128 * 768) {
            int n = idx / 768, kk = idx % 768;
            int kz = kk & 255;
            float v = Wh1[(size_t)kz * 128 + n];
            unsigned short hi = f2bf(v);
            wt[OFF_H + idx] = (kk < 512) ? hi : f2bf(v - bf2f(hi));
        }
    } else if (b < 2128) {
        // ---- km_frag: per-lane attention bias fragments, BOTH layers ----
        int tile = b - 1104;               // [0,1024)
        int kt = tile >> 5, qb = tile & 31;
        float s0 = bias_w[0] * LOG2E, s1 = bias_w[1] * LOG2E;
        int q0 = qb * 64 + ((t >> 6) << 4) + (((t >> 4) & 3) << 2);
        int k0 = kt * 64 + (t & 15);
        u16x8 a0, a1, b0, b1;
        #pragma unroll
        for (int c = 0; c < 4; c++)
            #pragma unroll
            for (int r = 0; r < 4; r++) {
                float v = Kmat[(size_t)(q0 + r) * L_LEN + k0 + c * 16];
                if (c < 2) { a0[c * 4 + r] = f2bf(v * s0); b0[c * 4 + r] = f2bf(v * s1); }
                else       { a1[(c - 2) * 4 + r] = f2bf(v * s0); b1[(c - 2) * 4 + r] = f2bf(v * s1); }
            }
        unsigned short* dp = kmfrag + (((size_t)(kt * 32 + qb)) * 256 + t) * 16;
        *(u16x8*)dp = a0;
        *(u16x8*)(dp + 8) = a1;
        unsigned short* dp1 = dp + ((size_t)1 << 22);
        *(u16x8*)dp1 = b0;
        *(u16x8*)(dp1 + 8) = b1;
    } else if (b < 2140) {
        // ---- fused QKV bias ----
        int idx = (b - 2128) * 256 + t;
        if (idx < 2 * 1536) {
            int i = idx / 1536, c = idx % 1536;
            float v;
            if (c < 512)       v = bq[i * 512 + c] * QSC;
            else if (c < 1024) v = bk[i * 512 + c - 512];
            else               v = bv[i * 512 + c - 1024];
            bqkv[idx] = v;
        }
    } else {
        // ---- feats: 4 elems/thread, both b rows from one read ----
        int idx = (b - 2140) * 256 + t;    // [0, 294912)
        int l = idx / 144;
        int f0 = (idx % 144) * 4;
        u16x4 pk0, pk1;
        #pragma unroll
        for (int j = 0; j < 4; j++) {
            int f = f0 + j;
            float val;
            if (f >= 3 && f < 506)      val = embed[(size_t)l * E_SZ + (f - 3)];
            else if (f >= 1 && f < 3)   val = s[l * S_SZ + (f - 1)];
            else if (f >= 506 && f < FIN) val = cond[f - 506];
            else                        val = 0.0f;
            unsigned short hv = f2bf(val);
            pk0[j] = (f == 0) ? f2bf(z[l]) : hv;
            pk1[j] = (f == 0) ? f2bf(z[L_LEN + l]) : hv;
        }
        *(u16x4*)(feats + (size_t)l * FIN_PAD + f0) = pk0;
        *(u16x4*)(feats + (size_t)(L_LEN + l) * FIN_PAD + f0) = pk1;
    }
}

// ---------------------------------------------------------------------------
// Wide-tile bf16 MFMA GEMM: 64x128 per block, 4 waves each 32x64 (2x4 frags),
// gll16 staging + XOR-swizzled LDS, double-buffered.
// OMODE: 1 = bf16 out, 4 = fused QKV routing
// ---------------------------------------------------------------------------
template<int ACT, int OMODE>
__global__ __launch_bounds__(256) void gemmW(
    const unsigned short* __restrict__ A, const unsigned short* __restrict__ Wt,
    const float* __restrict__ bias, unsigned short* __restrict__ Cb,
    unsigned short* __restrict__ Cbk, unsigned short* __restrict__ Cbv,
    int M, int N, int Kd, int lda)
{
    __shared__ unsigned short sA[2][64][64];
    __shared__ unsigned short sB[2][128][64];
    const int tid = threadIdx.x;
    const int l = tid & 63, w = tid >> 6;
    const int g = l >> 4, n16 = l & 15;
    const int wr = w >> 1, wc = w & 1;
    const int m0 = blockIdx.y * 64, n0 = blockIdx.x * 128;
    const int r8 = l >> 3;
    const int swz8 = ((l & 7) ^ r8) * 8;

    f32x4 acc[2][4];
    #pragma unroll
    for (int mi = 0; mi < 2; mi++)
        #pragma unroll
        for (int ni = 0; ni < 4; ni++)
            acc[mi][ni] = (f32x4){0.f, 0.f, 0.f, 0.f};

#define STAGEW(buf, k0)                                                         \
    do {                                                                        \
        _Pragma("unroll")                                                       \
        for (int p = 0; p < 2; p++) {                                           \
            int row = w * 16 + p * 8 + r8;                                      \
            gll16(A + (size_t)(m0 + row) * lda + (k0) + swz8,                   \
                  &sA[buf][w * 16 + p * 8][0]);                                 \
        }                                                                       \
        _Pragma("unroll")                                                       \
        for (int p = 0; p < 4; p++) {                                           \
            int row = w * 32 + p * 8 + r8;                                      \
            gll16(Wt + (size_t)(n0 + row) * Kd + (k0) + swz8,                   \
                  &sB[buf][w * 32 + p * 8][0]);                                 \
        }                                                                       \
    } while (0)

    STAGEW(0, 0);
    __syncthreads();

    int cur = 0;
    for (int k0 = 0; k0 < Kd; k0 += 64) {
        int nxt = cur ^ 1;
        if (k0 + 64 < Kd) STAGEW(nxt, k0 + 64);
        #pragma unroll
        for (int ks = 0; ks < 2; ks++) {
            bf16x8 af[2], bfr[4];
            #pragma unroll
            for (int mi = 0; mi < 2; mi++) {
                int row = wr * 32 + mi * 16 + n16;
                af[mi] = *(const bf16x8*)((const char*)&sA[cur][row][0]
                          + ((ks * 64 + g * 16) ^ ((n16 & 7) << 4)));
            }
            #pragma unroll
            for (int ni = 0; ni < 4; ni++) {
                int row = wc * 64 + ni * 16 + n16;
                bfr[ni] = *(const bf16x8*)((const char*)&sB[cur][row][0]
                          + ((ks * 64 + g * 16) ^ ((n16 & 7) << 4)));
            }
            #pragma unroll
            for (int mi = 0; mi < 2; mi++)
                #pragma unroll
                for (int ni = 0; ni < 4; ni++)
                    acc[mi][ni] = __builtin_amdgcn_mfma_f32_16x16x32_bf16(
                        af[mi], bfr[ni], acc[mi][ni], 0, 0, 0);
        }
        __syncthreads();
        cur = nxt;
    }
#undef STAGEW

    #pragma unroll
    for (int mi = 0; mi < 2; mi++) {
        #pragma unroll
        for (int ni = 0; ni < 4; ni++) {
            int col = n0 + wc * 64 + ni * 16 + n16;
            float bv = bias[col];
            #pragma unroll
            for (int r = 0; r < 4; r++) {
                int row = m0 + wr * 32 + mi * 16 + 4 * g + r;
                float val = acc[mi][ni][r] + bv;
                if (ACT == 1) val = gelu_f(val);
                if (OMODE == 1) {
                    Cb[(size_t)row * N + col] = f2bf(val);
                } else {
                    if (col < 1024) {
                        unsigned short* dst = (col < 512) ? Cb : Cbk;
                        dst[(size_t)row * 512 + (col & 511)] = f2bf(val);
                    } else {
                        Cbv[((size_t)(row >> 11) * 512 + (col - 1024)) * L_LEN + (row & (L_LEN - 1))] = f2bf(val);
                    }
                }
            }
        }
    }
}

// ---------------------------------------------------------------------------
// 64-wide bf16 MFMA GEMM (double-buffered). BM = 64, 32, or 16.
// OMODE: 0 = f32 out, 1 = bf16 out, 2 = f32 +=, 5 = f32-residual + split-bf16
// ---------------------------------------------------------------------------
template<int ACT, int OMODE, int BM>
__global__ __launch_bounds__(256) void gemm_bf16(
    const unsigned short* __restrict__ A, const unsigned short* __restrict__ Wt,
    const float* __restrict__ bias, float* __restrict__ Cf,
    unsigned short* __restrict__ Cb, int M, int N, int Kd, int lda)
{
    __shared__ unsigned short sA[2][BM][64];
    __shared__ unsigned short sB[2][64][64];
    const int tid = threadIdx.x;
    const int l = tid & 63, w = tid >> 6;
    const int g = l >> 4, n16 = l & 15;
    const int m0 = blockIdx.y * BM, n0 = blockIdx.x * 64;

    const int r8 = l >> 3;
    const int swz8 = ((l & 7) ^ r8) * 8;

    const int NMI = (BM == 64) ? 2 : 1;
    const int NNI = (BM == 16) ? 1 : 2;
    const int wr = w >> 1;
    const int wc = w & 1;

    f32x4 acc[2][2];
    #pragma unroll
    for (int mi = 0; mi < 2; mi++)
        #pragma unroll
        for (int ni = 0; ni < 2; ni++)
            acc[mi][ni] = (f32x4){0.f, 0.f, 0.f, 0.f};

#define STAGE(buf, k0)                                                          \
    do {                                                                        \
        if (BM == 64) {                                                         \
            _Pragma("unroll")                                                   \
            for (int p = 0; p < 2; p++) {                                       \
                int row = w * 16 + p * 8 + r8;                                  \
                gll16(A + (size_t)(m0 + row) * lda + (k0) + swz8,               \
                      &sA[buf][w * 16 + p * 8][0]);                             \
            }                                                                   \
        } else if (BM == 32) {                                                  \
            int row = w * 8 + r8;                                               \
            gll16(A + (size_t)(m0 + row) * lda + (k0) + swz8,                   \
                  &sA[buf][w * 8][0]);                                          \
        } else {                                                                \
            if (w < 2) {                                                        \
                int row = w * 8 + r8;                                           \
                gll16(A + (size_t)(m0 + row) * lda + (k0) + swz8,               \
                      &sA[buf][w * 8][0]);                                      \
            }                                                                   \
        }                                                                       \
        _Pragma("unroll")                                                       \
        for (int p = 0; p < 2; p++) {                                           \
            int row = w * 16 + p * 8 + r8;                                      \
            gll16(Wt + (size_t)(n0 + row) * Kd + (k0) + swz8,                   \
                  &sB[buf][w * 16 + p * 8][0]);                                 \
        }                                                                       \
    } while (0)

    STAGE(0, 0);
    __syncthreads();

    int cur = 0;
    for (int k0 = 0; k0 < Kd; k0 += 64) {
        int nxt = cur ^ 1;
        if (k0 + 64 < Kd) STAGE(nxt, k0 + 64);
        #pragma unroll
        for (int ks = 0; ks < 2; ks++) {
            bf16x8 af[2], bfr[2];
            #pragma unroll
            for (int mi = 0; mi < NMI; mi++) {
                int row = (BM == 64) ? (wr * 32 + mi * 16 + n16)
                        : (BM == 32) ? (wr * 16 + n16) : n16;
                af[mi] = *(const bf16x8*)((const char*)&sA[cur][row][0]
                          + ((ks * 64 + g * 16) ^ ((n16 & 7) << 4)));
            }
            #pragma unroll
            for (int ni = 0; ni < NNI; ni++) {
                int row = (BM == 16) ? (w * 16 + n16) : (wc * 32 + ni * 16 + n16);
                bfr[ni] = *(const bf16x8*)((const char*)&sB[cur][row][0]
                          + ((ks * 64 + g * 16) ^ ((n16 & 7) << 4)));
            }
            #pragma unroll
            for (int mi = 0; mi < NMI; mi++)
                #pragma unroll
                for (int ni = 0; ni < NNI; ni++)
                    acc[mi][ni] = __builtin_amdgcn_mfma_f32_16x16x32_bf16(
                        af[mi], bfr[ni], acc[mi][ni], 0, 0, 0);
        }
        __syncthreads();
        cur = nxt;
    }
#undef STAGE

    #pragma unroll
    for (int mi = 0; mi < NMI; mi++) {
        #pragma unroll
        for (int ni = 0; ni < NNI; ni++) {
            int col = (BM == 16) ? (n0 + w * 16 + n16)
                                 : (n0 + wc * 32 + ni * 16 + n16);
            float bv = bias[col];
            #pragma unroll
            for (int r = 0; r < 4; r++) {
                int row = (BM == 64) ? (m0 + wr * 32 + mi * 16 + 4 * g + r)
                        : (BM == 32) ? (m0 + wr * 16 + 4 * g + r)
                                     : (m0 + 4 * g + r);
                float val = acc[mi][ni][r] + bv;
                if (ACT == 1) val = gelu_f(val);
                if (OMODE == 0) {
                    Cf[(size_t)row * N + col] = val;
                } else if (OMODE == 1) {
                    Cb[(size_t)row * N + col] = f2bf(val);
                } else if (OMODE == 2) {
                    float* cp = Cf + (size_t)row * N + col;
                    *cp += val;
                } else if (OMODE == 5) {
                    float xnew = Cf[(size_t)row * N + col] + val;
                    unsigned short hi = f2bf(xnew);
                    unsigned short lo = f2bf(xnew - bf2f(hi));
                    unsigned short* orow = Cb + (size_t)row * 768;
                    orow[col] = hi;
                    orow[256 + col] = lo;
                    orow[512 + col] = hi;
                }
            }
        }
    }
}

// ---------------------------------------------------------------------------
// LayerNorm: x f32 -> h bf16
// ---------------------------------------------------------------------------
__global__ __launch_bounds__(256) void ln_bf16(
    const float* __restrict__ x, const float* __restrict__ sc,
    const float* __restrict__ bi, unsigned short* __restrict__ out)
{
    int wave = threadIdx.x >> 6, lane = threadIdx.x & 63;
    int row = blockIdx.x * 4 + wave;
    const float* xr = x + (size_t)row * D_MOD;
    float4 v = *(const float4*)(xr + lane * 4);
    float s1 = v.x + v.y + v.z + v.w;
    float s2 = v.x * v.x + v.y * v.y + v.z * v.z + v.w * v.w;
    #pragma unroll
    for (int off = 1; off < 64; off <<= 1) {
        s1 += __shfl_xor(s1, off);
        s2 += __shfl_xor(s2, off);
    }
    float mean = s1 * (1.0f / 256.0f);
    float var = s2 * (1.0f / 256.0f) - mean * mean;
    float rs = rsqrtf(var + 1e-6f);
    float4 scv = *(const float4*)(sc + lane * 4);
    float4 bv  = *(const float4*)(bi + lane * 4);
    u16x4 o4;
    o4[0] = f2bf((v.x - mean) * rs * scv.x + bv.x);
    o4[1] = f2bf((v.y - mean) * rs * scv.y + bv.y);
    o4[2] = f2bf((v.z - mean) * rs * scv.z + bv.z);
    o4[3] = f2bf((v.w - mean) * rs * scv.w + bv.w);
    *(u16x4*)(out + (size_t)row * D_MOD + lane * 4) = o4;
}

// ---------------------------------------------------------------------------
// MFMA flash attention, split-K x2: grid 1024 = 4 blocks/CU. Each block does
// 16 k-tiles (half the key range) for 64 q rows of one (b,hh). Fixed-max
// softmax -> partials combine exactly. km bias via per-lane register
// fragments (coalesced). One barrier per tile. sP XOR-swizzled (no pad) so
// LDS = 40960 B -> 4 blocks/CU. Writes unnormalized bf16 o + f32 l.
// ---------------------------------------------------------------------------
__global__ __launch_bounds__(256, 4) void attn_mfma(
    const unsigned short* __restrict__ q, const unsigned short* __restrict__ k,
    const unsigned short* __restrict__ vt, const unsigned short* __restrict__ kmf,
    unsigned short* __restrict__ po, float* __restrict__ pl)
{
    __shared__ unsigned short sK[2][64][64];
    __shared__ unsigned short sV[2][64][64];    // V^T tile [d][key]
    __shared__ unsigned short sP[4][16][64];    // XOR-swizzled, no pad

    const int tid = threadIdx.x;
    const int l = tid & 63, w = tid >> 6;
    const int g = l >> 4, n16 = l & 15;

    // XCD-aware decomposition of the 1D 1024-block grid
    const int id = blockIdx.x;
    const int xcd = id & 7, rest = id >> 3;     // rest 0..127
    const int panel = xcd * 2 + (rest & 1);
    const int sub = rest >> 1;                  // 0..63
    const int half = sub & 1;
    const int qi = sub >> 1;                    // 0..31
    const int qblk = qi * 64, hh = panel & 7, b = panel >> 3;
    const int kv0 = half * 1024;

    const int r8 = l >> 3;
    const int swz8 = ((l & 7) ^ r8) * 8;

    bf16x8 qf[2];
    {
        const unsigned short* qp = q + (size_t)(b * L_LEN + qblk + w * 16 + n16) * 512 + hh * 64;
        qf[0] = *(const bf16x8*)(qp + g * 8);
        qf[1] = *(const bf16x8*)(qp + 32 + g * 8);
    }
    bf16x8 onesf;
    #pragma unroll
    for (int j = 0; j < 8; j++) onesf[j] = (short)0x3F80;

    f32x4 o_acc[4];
    #pragma unroll
    for (int c = 0; c < 4; c++) o_acc[c] = (f32x4){0.f, 0.f, 0.f, 0.f};
    f32x4 l_acc = (f32x4){0.f, 0.f, 0.f, 0.f};

    const unsigned short* kbase = k + ((size_t)(b * L_LEN) + kv0) * 512 + hh * 64;
    const unsigned short* vbase = vt + ((size_t)b * 512 + hh * 64) * L_LEN + kv0;
    const unsigned short* kmbase = kmf + (((size_t)qi * 256 + tid) * 16)
                                 + (size_t)(half * 16) * 131072;

    // ---- prologue: tile 0 ----
    #pragma unroll
    for (int p = 0; p < 2; p++) {
        int row = w * 16 + p * 8 + r8;
        gll16(kbase + (size_t)row * 512 + swz8, &sK[0][w * 16 + p * 8][0]);
        gll16(vbase + (size_t)row * L_LEN + swz8, &sV[0][w * 16 + p * 8][0]);
    }
    u16x8 kmC0 = *(const u16x8*)kmbase;
    u16x8 kmC1 = *(const u16x8*)(kmbase + 8);
    __syncthreads();

    int cur = 0;
    for (int kt = 0; kt < 16; kt++) {
        const int nb = cur ^ 1;
        const int kblk2 = (kt + 1) << 6;
        u16x8 kmN0 = kmC0, kmN1 = kmC1;
        if (kt + 1 < 16) {
            #pragma unroll
            for (int p = 0; p < 2; p++) {
                int row = w * 16 + p * 8 + r8;
                gll16(kbase + (size_t)(kblk2 + row) * 512 + swz8, &sK[nb][w * 16 + p * 8][0]);
                gll16(vbase + (size_t)row * L_LEN + kblk2 + swz8, &sV[nb][w * 16 + p * 8][0]);
            }
            const unsigned short* kp2 = kmbase + (size_t)(kt + 1) * 131072;
            kmN0 = *(const u16x8*)kp2;
            kmN1 = *(const u16x8*)(kp2 + 8);
        }
        // ---- km fragment -> MFMA C-init ----
        f32x4 sacc[4];
        #pragma unroll
        for (int c = 0; c < 4; c++)
            #pragma unroll
            for (int r = 0; r < 4; r++)
                sacc[c][r] = bf2f((unsigned short)(c < 2 ? kmC0[c * 4 + r] : kmC1[(c - 2) * 4 + r]));
        // ---- QK^T (accumulates onto km) ----
        __builtin_amdgcn_s_setprio(1);
        #pragma unroll
        for (int ks = 0; ks < 2; ks++)
            #pragma unroll
            for (int c = 0; c < 4; c++) {
                int row = c * 16 + n16;
                bf16x8 kf = *(const bf16x8*)((const char*)&sK[cur][row][0]
                             + ((ks * 64 + g * 16) ^ ((n16 & 7) << 4)));
                sacc[c] = __builtin_amdgcn_mfma_f32_16x16x32_bf16(qf[ks], kf, sacc[c], 0, 0, 0);
            }
        __builtin_amdgcn_s_setprio(0);
        // ---- p = exp2(score) ----
        float p[4][4];
        #pragma unroll
        for (int r = 0; r < 4; r++)
            #pragma unroll
            for (int c = 0; c < 4; c++)
                p[r][c] = __builtin_amdgcn_exp2f(sacc[c][r]);
        // ---- P -> per-wave LDS (bf16), XOR-swizzled cols ----
        #pragma unroll
        for (int r = 0; r < 4; r++) {
            int prow = 4 * g + r;
            #pragma unroll
            for (int c = 0; c < 4; c++)
                sP[w][prow][(c * 16 + n16) ^ ((prow & 7) << 3)] = f2bf(p[r][c]);
        }
        // ---- PV + l-sum ----
        __builtin_amdgcn_s_setprio(1);
        #pragma unroll
        for (int ks = 0; ks < 2; ks++) {
            bf16x8 pf = *(const bf16x8*)((const char*)&sP[w][n16][0]
                         + (((ks * 32 + g * 8) ^ ((n16 & 7) << 3)) * 2));
            l_acc = __builtin_amdgcn_mfma_f32_16x16x32_bf16(pf, onesf, l_acc, 0, 0, 0);
            #pragma unroll
            for (int c = 0; c < 4; c++) {
                int row = c * 16 + n16;
                bf16x8 vf = *(const bf16x8*)((const char*)&sV[cur][row][0]
                             + ((ks * 64 + g * 16) ^ ((n16 & 7) << 4)));
                o_acc[c] = __builtin_amdgcn_mfma_f32_16x16x32_bf16(pf, vf, o_acc[c], 0, 0, 0);
            }
        }
        __builtin_amdgcn_s_setprio(0);
        __syncthreads();   // single barrier: drains next-tile gll16, syncs buf reuse
        cur = nb;
        kmC0 = kmN0;
        kmC1 = kmN1;
    }

    // ---- epilogue: unnormalized partials (bf16 o, f32 l) ----
    unsigned short* pob = po + (size_t)half * (4096 * 512);
    #pragma unroll
    for (int c = 0; c < 4; c++)
        #pragma unroll
        for (int r = 0; r < 4; r++)
            pob[(size_t)(b * L_LEN + qblk + w * 16 + 4 * g + r) * 512 + hh * 64 + c * 16 + n16]
                = f2bf(o_acc[c][r]);
    if (n16 == 0) {
        #pragma unroll
        for (int r = 0; r < 4; r++)
            pl[(size_t)half * 32768 + (size_t)(b * L_LEN + qblk + w * 16 + 4 * g + r) * 8 + hh]
                = l_acc[r];
    }
}

// ---------------------------------------------------------------------------
// Combine split-K partials: ob = (po0+po1)/(l0+l1), bf16. 8 elems/thread.
// ---------------------------------------------------------------------------
__global__ __launch_bounds__(256) void attn_combine(
    const unsigned short* __restrict__ po, const float* __restrict__ pl,
    unsigned short* __restrict__ ob)
{
    int idx = (blockIdx.x * 256 + threadIdx.x) * 8;   // into 4096*512
    int row = idx >> 9, hh = (idx & 511) >> 6;
    u16x8 a = *(const u16x8*)(po + idx);
    u16x8 b8 = *(const u16x8*)(po + (size_t)(4096 * 512) + idx);
    float l0 = pl[(size_t)row * 8 + hh];
    float l1 = pl[32768 + (size_t)row * 8 + hh];
    float inv = 1.0f / (l0 + l1);
    u16x8 o;
    #pragma unroll
    for (int j = 0; j < 8; j++)
        o[j] = f2bf((bf2f((unsigned short)a[j]) + bf2f((unsigned short)b8[j])) * inv);
    *(u16x8*)(ob + idx) = o;
}

// ---------------------------------------------------------------------------
// Fused head: out[row] = dot(gelu(xb[row] @ Whb + bh1) * Wh2) + bh2
// One block = 16 rows x 128 cols (wave w -> cols w*32..w*32+31). K=768.
// ---------------------------------------------------------------------------
__global__ __launch_bounds__(256) void head_kernel(
    const unsigned short* __restrict__ A, const unsigned short* __restrict__ Wt,
    const float* __restrict__ bh1, const float* __restrict__ Wh2,
    const float* __restrict__ bh2, float* __restrict__ out)
{
    __shared__ unsigned short sA[2][16][64];
    __shared__ unsigned short sB[2][128][64];
    __shared__ float sRed[4][16];
    const int tid = threadIdx.x;
    const int l = tid & 63, w = tid >> 6;
    const int g = l >> 4, n16 = l & 15;
    const int m0 = blockIdx.x * 16;
    const int r8 = l >> 3;
    const int swz8 = ((l & 7) ^ r8) * 8;

    f32x4 acc[2];
    acc[0] = (f32x4){0.f, 0.f, 0.f, 0.f};
    acc[1] = (f32x4){0.f, 0.f, 0.f, 0.f};

#define HSTAGE(buf, k0)                                                         \
    do {                                                                        \
        if (w < 2) {                                                            \
            int row = w * 8 + r8;                                               \
            gll16(A + (size_t)(m0 + row) * 768 + (k0) + swz8,                   \
                  &sA[buf][w * 8][0]);                                          \
        }                                                                       \
        _Pragma("unroll")                                                       \
        for (int p = 0; p < 4; p++) {                                           \
            int row = w * 32 + p * 8 + r8;                                      \
            gll16(Wt + (size_t)row * 768 + (k0) + swz8,                         \
                  &sB[buf][w * 32 + p * 8][0]);                                 \
        }                                                                       \
    } while (0)

    HSTAGE(0, 0);
    __syncthreads();

    int cur = 0;
    for (int k0 = 0; k0 < 768; k0 += 64) {
        int nxt = cur ^ 1;
        if (k0 + 64 < 768) HSTAGE(nxt, k0 + 64);
        #pragma unroll
        for (int ks = 0; ks < 2; ks++) {
            bf16x8 af = *(const bf16x8*)((const char*)&sA[cur][n16][0]
                         + ((ks * 64 + g * 16) ^ ((n16 & 7) << 4)));
            #pragma unroll
            for (int ni = 0; ni < 2; ni++) {
                int row = w * 32 + ni * 16 + n16;
                bf16x8 bfr = *(const bf16x8*)((const char*)&sB[cur][row][0]
                              + ((ks * 64 + g * 16) ^ ((n16 & 7) << 4)));
                acc[ni] = __builtin_amdgcn_mfma_f32_16x16x32_bf16(af, bfr, acc[ni], 0, 0, 0);
            }
        }
        __syncthreads();
        cur = nxt;
    }
#undef HSTAGE

    float s[4];
    #pragma unroll
    for (int r = 0; r < 4; r++) {
        s[r] = 0.f;
        #pragma unroll
        for (int ni = 0; ni < 2; ni++) {
            int col = w * 32 + ni * 16 + n16;
            s[r] += gelu_f(acc[ni][r] + bh1[col]) * Wh2[col];
        }
        s[r] += __shfl_xor(s[r], 1);
        s[r] += __shfl_xor(s[r], 2);
        s[r] += __shfl_xor(s[r], 4);
        s[r] += __shfl_xor(s[r], 8);
    }
    if (n16 == 0) {
        #pragma unroll
        for (int r = 0; r < 4; r++) sRed[w][4 * g + r] = s[r];
    }
    __syncthreads();
    if (tid < 16)
        out[m0 + tid] = sRed[0][tid] + sRed[1][tid] + sRed[2][tid] + sRed[3][tid] + bh2[0];
}

// ---------------------------------------------------------------------------
extern "C" void kernel_launch(void* const* d_in, const int* in_sizes, int n_in,
                              void* d_out, int out_size, void* d_ws, size_t ws_size,
                              hipStream_t stream)
{
    const float* z      = (const float*)d_in[0];
    const float* cond   = (const float*)d_in[1];
    const float* s      = (const float*)d_in[2];
    const float* Kmat   = (const float*)d_in[3];
    const float* embed  = (const float*)d_in[4];
    const float* W_in1  = (const float*)d_in[5];
    const float* b_in1  = (const float*)d_in[6];
    const float* W_in2  = (const float*)d_in[7];
    const float* b_in2  = (const float*)d_in[8];
    const float* bias_w = (const float*)d_in[9];
    const float* bias_b = (const float*)d_in[10];  // cancels in softmax
    const float* Wq     = (const float*)d_in[11];
    const float* bq     = (const float*)d_in[12];
    const float* Wk     = (const float*)d_in[13];
    const float* bk     = (const float*)d_in[14];
    const float* Wv     = (const float*)d_in[15];
    const float* bv     = (const float*)d_in[16];
    const float* Wo     = (const float*)d_in[17];
    const float* bo     = (const float*)d_in[18];
    const float* ln1_s  = (const float*)d_in[19];
    const float* ln1_b  = (const float*)d_in[20];
    const float* ln2_s  = (const float*)d_in[21];
    const float* ln2_b  = (const float*)d_in[22];
    const float* Wf1    = (const float*)d_in[23];
    const float* bf1    = (const float*)d_in[24];
    const float* Wf2    = (const float*)d_in[25];
    const float* bf2    = (const float*)d_in[26];
    const float* Wh1    = (const float*)d_in[27];
    const float* bh1    = (const float*)d_in[28];
    const float* Wh2    = (const float*)d_in[29];
    const float* bh2    = (const float*)d_in[30];
    float* out = (float*)d_out;
    (void)bias_b;

    const int M = B_SZ * L_LEN; // 4096
    char* base = (char*)d_ws;
    unsigned short* feats = (unsigned short*)base;                     // 4096*576 bf16
    float* x = (float*)(base + (size_t)M * FIN_PAD * 2);               // 4096*256 f32
    unsigned short* h    = (unsigned short*)((char*)x + (size_t)M * D_MOD * 4);
    unsigned short* hid1 = h    + (size_t)M * D_MOD;                   // 4096*1024
    unsigned short* qb   = hid1 + (size_t)M * 1024;                    // 4096*512 (also head xb [4096][768] with kb2)
    unsigned short* kb2  = qb   + (size_t)M * 512;
    unsigned short* vtb  = kb2  + (size_t)M * 512;                     // [2][512][2048]
    unsigned short* ob   = vtb  + (size_t)M * 512;
    unsigned short* wt   = ob   + (size_t)M * 512;                     // WT_END elems
    float* bqkv          = (float*)(wt + WT_END);                      // 2*1536 f32
    unsigned short* kmfrag = (unsigned short*)(bqkv + 2 * 1536);       // [2][1<<22]
    unsigned short* po   = kmfrag + ((size_t)2 << 22);                 // [2][4096][512] bf16
    float* pl            = (float*)(po + (size_t)2 * 4096 * 512);      // [2][4096][8] f32

    prep_kernel<<<dim3(3292), dim3(256), 0, stream>>>(
        W_in1, W_in2, Wq, Wk, Wv, Wo, Wf1, Wf2, Wh1, Kmat, bias_w,
        bq, bk, bv, z, s, embed, cond, wt, kmfrag, bqkv, feats);

    gemmW<1, 1><<<dim3(8, 64), 256, 0, stream>>>(feats, wt + OFF_IN1, b_in1, hid1, nullptr, nullptr, M, 1024, FIN_PAD, FIN_PAD);
    gemm_bf16<0, 0, 16><<<dim3(4, 256), 256, 0, stream>>>(hid1, wt + OFF_IN2, b_in2, x, nullptr, M, 256, 1024, 1024);

    for (int i = 0; i < NB_BLK; i++) {
        ln_bf16<<<dim3(M / 4), 256, 0, stream>>>(x, ln1_s + i * D_MOD, ln1_b + i * D_MOD, h);
        gemmW<0, 4><<<dim3(12, 64), 256, 0, stream>>>(h, wt + OFF_QKV + (size_t)i * 393216, bqkv + i * 1536, qb, kb2, vtb, M, 1536, 256, 256);
        attn_mfma<<<dim3(1024), 256, 0, stream>>>(qb, kb2, vtb, kmfrag + ((size_t)i << 22), po, pl);
        attn_combine<<<dim3(1024), 256, 0, stream>>>(po, pl, ob);
        gemm_bf16<0, 2, 16><<<dim3(4, 256), 256, 0, stream>>>(ob, wt + OFF_O + (size_t)i * 131072, bo + i * D_MOD, x, nullptr, M, 256, 512, 512);
        ln_bf16<<<dim3(M / 4), 256, 0, stream>>>(x, ln2_s + i * D_MOD, ln2_b + i * D_MOD, h);
        gemmW<1, 1><<<dim3(8, 64), 256, 0, stream>>>(h, wt + OFF_F1 + (size_t)i * 262144, bf1 + i * 1024, hid1, nullptr, nullptr, M, 1024, 256, 256);
        if (i == 0)
            gemm_bf16<0, 2, 16><<<dim3(4, 256), 256, 0, stream>>>(hid1, wt + OFF_F2 + (size_t)i * 262144, bf2 + i * D_MOD, x, nullptr, M, 256, 1024, 1024);
        else
            gemm_bf16<0, 5, 16><<<dim3(4, 256), 256, 0, stream>>>(hid1, wt + OFF_F2 + (size_t)i * 262144, bf2 + i * D_MOD, x, qb, M, 256, 1024, 1024);
    }
    head_kernel<<<dim3(256), 256, 0, stream>>>(qb, wt + OFF_H, bh1, Wh2, bh2, out);
}